// Round 6
// baseline (480.872 us; speedup 1.0000x reference)
//
#include <hip/hip_runtime.h>
#include <math.h>

#define N_NODES    100000
#define N_EDGES    1600000
#define HIDDEN     128
#define NUM_GRAPHS 64

constexpr int POOL_CHUNKS = 16;
constexpr int PADK        = 132;

// bucketed CSR build
constexpr int BSHIFT = 3;                    // 8 nodes per bucket
constexpr int NPB    = 1 << BSHIFT;          // 8
constexpr int NBUCK  = N_NODES >> BSHIFT;    // 12500 (exact)
constexpr int BCAP   = 224;                  // mean 128, +8.5 sigma; 896B = 7 cache lines, line-aligned
constexpr int NPART  = 8;                    // one partition per XCD
constexpr int PPART  = (NBUCK + NPART - 1) / NPART;  // 1563 cursors per partition
constexpr int EPB    = 2048;                 // edges per block-chunk
constexpr int NCHUNK = (N_EDGES + EPB - 1) / EPB;    // 782

// cursor reindex: partition-major so counter cache lines are XCD-private
static __device__ __forceinline__ int curidx(int b) {
    return (b & (NPART - 1)) * PPART + (b >> 3);
}

// bf16 helpers (RNE)
static __device__ __forceinline__ unsigned short f2bf(float f) {
    unsigned u = __float_as_uint(f);
    u += 0x7FFFu + ((u >> 16) & 1u);
    return (unsigned short)(u >> 16);
}
static __device__ __forceinline__ float b2f(unsigned short h) {
    return __uint_as_float(((unsigned)h) << 16);
}

// ---------------- graph boundaries (batch is sorted) ----------------

__global__ void k_gbounds(const int* __restrict__ batch, int* __restrict__ gstart) {
    int i = blockIdx.x * blockDim.x + threadIdx.x;
    if (i >= N_NODES) return;
    int b = batch[i];
    if (i == 0) {
        for (int g = 0; g <= b; ++g) gstart[g] = 0;
    } else {
        int bp = batch[i - 1];
        for (int g = bp + 1; g <= b; ++g) gstart[g] = i;
    }
    if (i == N_NODES - 1) {
        for (int g = b + 1; g <= NUM_GRAPHS; ++g) gstart[g] = N_NODES;
    }
}

// ---------------- bucketed CSR build ----------------

__global__ void k_bzero(int* bcnt) {
    int i = blockIdx.x * blockDim.x + threadIdx.x;
    if (i < NPART * PPART) bcnt[i] = 0;
}

// pass 1, XCD-partitioned: block (chunk = blockIdx>>3, part = blockIdx&7) scans its
// chunk and appends only edges whose bucket belongs to its partition. blockIdx%8
// round-robins to XCDs, so each bucket's slab lines are written by ONE XCD's L2
// and merge fully before writeback (kills the 14x partial-line write amplification).
__global__ __launch_bounds__(256) void k_p1(const int* __restrict__ src,
                                            const int* __restrict__ dst,
                                            int* bcnt, unsigned* __restrict__ bidx) {
    const int part  = blockIdx.x & (NPART - 1);
    const int chunk = blockIdx.x >> 3;
    const int e0    = chunk * EPB + threadIdx.x;
    #pragma unroll
    for (int it = 0; it < EPB / 256; ++it) {
        int e = e0 + it * 256;
        if (e < N_EDGES) {
            int d = dst[e];
            int b = d >> BSHIFT;
            if ((b & (NPART - 1)) == part) {
                int s = src[e];
                int pos = atomicAdd(&bcnt[curidx(b)], 1);
                if (pos < BCAP)
                    bidx[(size_t)b * BCAP + pos] = ((unsigned)s << BSHIFT) | (unsigned)(d & (NPB - 1));
            }
        }
    }
}

// exclusive scan of clamped bucket counts (single block, 1024 threads)
__global__ __launch_bounds__(1024) void k_bscan(const int* __restrict__ bcnt,
                                                int* __restrict__ bbase) {
    __shared__ int tsum[1024];
    const int PER = (NBUCK + 1023) / 1024;   // 13
    int t = threadIdx.x;
    int lo = t * PER, hi = lo + PER < NBUCK ? lo + PER : NBUCK;
    int s = 0;
    for (int i = lo; i < hi; ++i) { int c = bcnt[curidx(i)]; s += (c < BCAP ? c : BCAP); }
    tsum[t] = s;
    __syncthreads();
    for (int off = 1; off < 1024; off <<= 1) {
        int add = (t >= off) ? tsum[t - off] : 0;
        __syncthreads();
        tsum[t] += add;
        __syncthreads();
    }
    int run = tsum[t] - s;   // exclusive
    for (int i = lo; i < hi; ++i) {
        bbase[i] = run;
        int c = bcnt[curidx(i)]; run += (c < BCAP ? c : BCAP);
    }
    if (t == 1023) bbase[NBUCK] = tsum[1023];
}

// pass 2: per-bucket finalize -> csr_src (contiguous), offs, dinv
__global__ __launch_bounds__(64) void k_p2(const int* __restrict__ bcnt,
                                           const int* __restrict__ bbase,
                                           const unsigned* __restrict__ bidx,
                                           int* __restrict__ csr_src,
                                           int* __restrict__ offs,
                                           float* __restrict__ dinv) {
    int b = blockIdx.x;
    int t = threadIdx.x;
    int cnt  = bcnt[curidx(b)]; cnt = cnt < BCAP ? cnt : BCAP;
    int base = bbase[b];

    __shared__ int h[NPB];
    __shared__ int loff[NPB + 1];
    __shared__ int cur[NPB];
    __shared__ unsigned eb[BCAP];

    if (t < NPB) { h[t] = 0; cur[t] = 0; }
    __syncthreads();
    for (int i = t; i < cnt; i += 64) {
        unsigned v = bidx[(size_t)b * BCAP + i];
        eb[i] = v;
        atomicAdd(&h[v & (NPB - 1)], 1);
    }
    __syncthreads();
    if (t == 0) {
        int r = 0;
        #pragma unroll
        for (int j = 0; j < NPB; ++j) { loff[j] = r; r += h[j]; }
        loff[NPB] = r;
    }
    __syncthreads();
    if (t < NPB) {
        int node = b * NPB + t;
        offs[node] = base + loff[t];
        dinv[node] = rsqrtf((float)(h[t] + 1));   // +1 self-loop
    }
    if (b == NBUCK - 1 && t == 0) offs[N_NODES] = base + cnt;
    __syncthreads();
    for (int i = t; i < cnt; i += 64) {
        unsigned v = eb[i];
        int lo = v & (NPB - 1);
        int p = atomicAdd(&cur[lo], 1);
        csr_src[base + loff[lo] + p] = (int)(v >> BSHIFT);
    }
}

// ---------------- dense GEMM: Hb = dinv ⊙ (X @ W) in bf16 ----------------

__global__ __launch_bounds__(256) void k_gemm(const float* __restrict__ X,
                                              const float* __restrict__ W,
                                              const float* __restrict__ dinv,
                                              unsigned short* __restrict__ Hb) {
    __shared__ float Xl[128 * PADK];
    __shared__ float Wl[128 * 128];

    const int t    = threadIdx.x;
    const int row0 = blockIdx.x * 128;
    const int kk   = t >> 5;           // 0..7
    const int c4   = (t & 31) * 4;     // 0..124

    #pragma unroll
    for (int p = 0; p < 16; ++p) {
        int r = kk + p * 8;
        float4 wv = *(const float4*)&W[r * HIDDEN + c4];
        *(float4*)&Wl[r * HIDDEN + c4] = wv;
        int rg = row0 + r;
        rg = rg < N_NODES ? rg : N_NODES - 1;   // clamp (tail block)
        float4 xv = *(const float4*)&X[(size_t)rg * HIDDEN + c4];
        *(float4*)&Xl[r * PADK + c4] = xv;
    }
    __syncthreads();

    const int trow = t >> 4;   // 0..15
    const int tcol = t & 15;   // 0..15

    float4 accA[8], accB[8];
    #pragma unroll
    for (int r = 0; r < 8; ++r) {
        accA[r] = make_float4(0.f, 0.f, 0.f, 0.f);
        accB[r] = make_float4(0.f, 0.f, 0.f, 0.f);
    }

    #pragma unroll 4
    for (int k = 0; k < HIDDEN; ++k) {
        float4 wa = *(const float4*)&Wl[k * HIDDEN + tcol * 4];
        float4 wb = *(const float4*)&Wl[k * HIDDEN + 64 + tcol * 4];
        float xs[8];
        #pragma unroll
        for (int r = 0; r < 4; ++r) {
            xs[r]     = Xl[(trow * 4 + r) * PADK + k];
            xs[r + 4] = Xl[(64 + trow * 4 + r) * PADK + k];
        }
        #pragma unroll
        for (int r = 0; r < 8; ++r) {
            accA[r].x += xs[r] * wa.x; accA[r].y += xs[r] * wa.y;
            accA[r].z += xs[r] * wa.z; accA[r].w += xs[r] * wa.w;
            accB[r].x += xs[r] * wb.x; accB[r].y += xs[r] * wb.y;
            accB[r].z += xs[r] * wb.z; accB[r].w += xs[r] * wb.w;
        }
    }

    #pragma unroll
    for (int r = 0; r < 8; ++r) {
        int rloc = (r < 4) ? (trow * 4 + r) : (64 + trow * 4 + (r - 4));
        int row  = row0 + rloc;
        if (row < N_NODES) {
            float di = dinv[row];
            ushort4 oa, ob;
            oa.x = f2bf(accA[r].x * di); oa.y = f2bf(accA[r].y * di);
            oa.z = f2bf(accA[r].z * di); oa.w = f2bf(accA[r].w * di);
            ob.x = f2bf(accB[r].x * di); ob.y = f2bf(accB[r].y * di);
            ob.z = f2bf(accB[r].z * di); ob.w = f2bf(accB[r].w * di);
            *(ushort4*)&Hb[(size_t)row * HIDDEN + tcol * 4]      = oa;
            *(ushort4*)&Hb[(size_t)row * HIDDEN + 64 + tcol * 4] = ob;
        }
    }
}

// ---------------- fused aggregation over pre-scaled bf16 rows ----------------

template <bool OUT_BF16, bool BIAS, bool RELU, bool OUTSCALE>
__global__ __launch_bounds__(256) void k_aggregate(const unsigned short* __restrict__ Hb,
                                                   const int* __restrict__ offs,
                                                   const int* __restrict__ csr_src,
                                                   const float* __restrict__ dinv,
                                                   const float* __restrict__ bias,
                                                   void* __restrict__ outv) {
    int g    = threadIdx.x >> 5;       // node-in-block 0..7
    int lane = threadIdx.x & 31;
    int node = blockIdx.x * 8 + g;
    if (node >= N_NODES) return;
    int c4 = lane * 4;

    float di = dinv[node];
    ushort4 sv = *(const ushort4*)&Hb[(size_t)node * HIDDEN + c4];
    float4 acc;
    acc.x = b2f(sv.x); acc.y = b2f(sv.y); acc.z = b2f(sv.z); acc.w = b2f(sv.w);

    int j0 = offs[node], j1 = offs[node + 1];
    #pragma unroll 4
    for (int j = j0; j < j1; ++j) {
        int s = csr_src[j];
        ushort4 v = *(const ushort4*)&Hb[(size_t)s * HIDDEN + c4];
        acc.x += b2f(v.x); acc.y += b2f(v.y);
        acc.z += b2f(v.z); acc.w += b2f(v.w);
    }

    acc.x *= di; acc.y *= di; acc.z *= di; acc.w *= di;
    if (BIAS) {
        float4 bv = *(const float4*)&bias[c4];
        acc.x += bv.x; acc.y += bv.y; acc.z += bv.z; acc.w += bv.w;
    }
    if (RELU) {
        acc.x = fmaxf(acc.x, 0.f); acc.y = fmaxf(acc.y, 0.f);
        acc.z = fmaxf(acc.z, 0.f); acc.w = fmaxf(acc.w, 0.f);
    }
    if (OUTSCALE) {
        acc.x *= di; acc.y *= di; acc.z *= di; acc.w *= di;
    }
    if (OUT_BF16) {
        ushort4 o;
        o.x = f2bf(acc.x); o.y = f2bf(acc.y); o.z = f2bf(acc.z); o.w = f2bf(acc.w);
        *(ushort4*)&((unsigned short*)outv)[(size_t)node * HIDDEN + c4] = o;
    } else {
        *(float4*)&((float*)outv)[(size_t)node * HIDDEN + c4] = acc;
    }
}

// ---------------- pooling: segmented reduction, no atomics ----------------

__global__ __launch_bounds__(256) void k_pool2(const float* __restrict__ X,
                                               const int* __restrict__ gstart,
                                               float* __restrict__ part) {
    int g  = blockIdx.x;
    int ch = blockIdx.y;
    int start = gstart[g], end = gstart[g + 1];
    int len = end - start;
    int r0 = start + (int)((long long)len * ch / POOL_CHUNKS);
    int r1 = start + (int)((long long)len * (ch + 1) / POOL_CHUNKS);

    int rp = threadIdx.x >> 5;         // 0..7 rows in parallel
    int c4 = (threadIdx.x & 31) * 4;

    float4 acc = make_float4(0.f, 0.f, 0.f, 0.f);
    for (int r = r0 + rp; r < r1; r += 8) {
        float4 v = *(const float4*)&X[(size_t)r * HIDDEN + c4];
        acc.x += v.x; acc.y += v.y; acc.z += v.z; acc.w += v.w;
    }

    __shared__ float4 sh[256];
    sh[threadIdx.x] = acc;
    __syncthreads();
    #pragma unroll
    for (int off = 4; off >= 1; off >>= 1) {
        if (rp < off) {
            float4 o = sh[(rp + off) * 32 + (threadIdx.x & 31)];
            float4 m = sh[threadIdx.x];
            m.x += o.x; m.y += o.y; m.z += o.z; m.w += o.w;
            sh[threadIdx.x] = m;
        }
        __syncthreads();
    }
    if (rp == 0) {
        float4 v = sh[threadIdx.x];
        *(float4*)&part[((size_t)g * POOL_CHUNKS + ch) * HIDDEN + c4] = v;
    }
}

// ---------------- final: out = ((Σpart/cnt) @ W2 + b2) @ linW + linb ----------------

__global__ void k_final(const float* __restrict__ part, const int* __restrict__ gstart,
                        const float* __restrict__ W2, const float* __restrict__ b2,
                        const float* __restrict__ linW, const float* __restrict__ linb,
                        float* __restrict__ out) {
    __shared__ float m[HIDDEN];
    __shared__ float t[HIDDEN];
    int g = blockIdx.x;
    int c = threadIdx.x;
    float s = 0.f;
    #pragma unroll
    for (int ch = 0; ch < POOL_CHUNKS; ++ch)
        s += part[((size_t)g * POOL_CHUNKS + ch) * HIDDEN + c];
    float cnt = fmaxf((float)(gstart[g + 1] - gstart[g]), 1.0f);
    m[c] = s / cnt;
    __syncthreads();
    float acc = b2[c];
    #pragma unroll 4
    for (int k = 0; k < HIDDEN; ++k) acc += m[k] * W2[k * HIDDEN + c];
    t[c] = acc;
    __syncthreads();
    if (c < 16) {
        float o = linb[c];
        #pragma unroll 4
        for (int k = 0; k < HIDDEN; ++k) o += t[k] * linW[k * 16 + c];
        out[g * 16 + c] = o;
    }
}

// ---------------- launch ----------------

extern "C" void kernel_launch(void* const* d_in, const int* in_sizes, int n_in,
                              void* d_out, int out_size, void* d_ws, size_t ws_size,
                              hipStream_t stream) {
    const float* x     = (const float*)d_in[0];
    const int*   edge  = (const int*)d_in[1];   // [2, E] flat
    const int*   batch = (const int*)d_in[2];
    const float* Ws    = (const float*)d_in[3]; // [3,128,128]
    const float* bs    = (const float*)d_in[4]; // [3,128]
    const float* linW  = (const float*)d_in[5]; // [128,16]
    const float* linb  = (const float*)d_in[6]; // [16]
    float* out = (float*)d_out;

    const int* src = edge;
    const int* dst = edge + N_EDGES;

    // workspace layout
    float* bufA = (float*)d_ws;                       // N*128 fp32 (x1, then x3)
    unsigned* bidx = (unsigned*)bufA;                 // NBUCK*BCAP u32 (11.2MB) — CSR-build
                                                      // scratch only; dead before agg1 writes bufA
    float* bufBreg = bufA + (size_t)N_NODES * HIDDEN; // N*128 fp32-sized region, carved:
    unsigned short* hb  = (unsigned short*)bufBreg;                            // N*128 bf16
    unsigned short* x2b = (unsigned short*)bufBreg + (size_t)N_NODES * HIDDEN; // N*128 bf16
    float* dinv = bufBreg + (size_t)N_NODES * HIDDEN; // N
    float* part = dinv + N_NODES;                     // 64*16*128
    int* offs    = (int*)(part + NUM_GRAPHS * POOL_CHUNKS * HIDDEN); // N+1
    int* csr_src = offs + N_NODES + 1;                // E
    int* gstart  = csr_src + N_EDGES;                 // NUM_GRAPHS+1
    int* bcnt    = gstart + NUM_GRAPHS + 1;           // NPART*PPART
    int* bbase   = bcnt + NPART * PPART;              // NBUCK+1

    const int NB_N    = (N_NODES + 255) / 256;   // 391
    const int NB_ROW  = N_NODES / 8;             // 12500
    const int NB_GEMM = (N_NODES + 127) / 128;   // 782

    // bucketed CSR build (also produces offs, dinv)
    k_bzero<<<(NPART * PPART + 255) / 256, 256, 0, stream>>>(bcnt);
    k_p1<<<NCHUNK * NPART, 256, 0, stream>>>(src, dst, bcnt, bidx);
    k_bscan<<<1, 1024, 0, stream>>>(bcnt, bbase);
    k_p2<<<NBUCK, 64, 0, stream>>>(bcnt, bbase, bidx, csr_src, offs, dinv);
    k_gbounds<<<NB_N, 256, 0, stream>>>(batch, gstart);

    // layer 0: hb = dinv ⊙ (x@W0) ; x1 = relu(dinv*(Σ hb) + b0)         [fp32 out]
    k_gemm<<<NB_GEMM, 256, 0, stream>>>(x, Ws, dinv, hb);
    k_aggregate<false, true, true, false><<<NB_ROW, 256, 0, stream>>>(hb, offs, csr_src, dinv, bs, bufA);

    // layer 1: hb = dinv ⊙ (x1@W1) ; x2' = dinv*relu(dinv*(Σ hb) + b1)  [bf16 out, pre-scaled]
    k_gemm<<<NB_GEMM, 256, 0, stream>>>(bufA, Ws + HIDDEN * HIDDEN, dinv, hb);
    k_aggregate<true, true, true, true><<<NB_ROW, 256, 0, stream>>>(hb, offs, csr_src, dinv, bs + HIDDEN, x2b);

    // layer 2 (algebraic trick): x3 = dinv*(Σ x2') ; pool ; tiny GEMMs in k_final
    k_aggregate<false, false, false, false><<<NB_ROW, 256, 0, stream>>>(x2b, offs, csr_src, dinv, nullptr, bufA);
    k_pool2<<<dim3(NUM_GRAPHS, POOL_CHUNKS), 256, 0, stream>>>(bufA, gstart, part);

    k_final<<<NUM_GRAPHS, HIDDEN, 0, stream>>>(part, gstart,
                                               Ws + 2 * HIDDEN * HIDDEN, bs + 2 * HIDDEN,
                                               linW, linb, out);
}

// Round 7
// 475.268 us; speedup vs baseline: 1.0118x; 1.0118x over previous
//
#include <hip/hip_runtime.h>
#include <math.h>

#define N_NODES    100000
#define N_EDGES    1600000
#define HIDDEN     128
#define NUM_GRAPHS 64

constexpr int POOL_CHUNKS = 16;
constexpr int PADK        = 132;

// ---- two-level LDS-staged CSR build ----
constexpr int BINSHIFT = 10;
constexpr int BINSZ    = 1 << BINSHIFT;                  // 1024 nodes per bin
constexpr int NBIN     = (N_NODES + BINSZ - 1) / BINSZ;  // 98
constexpr int CH_E     = 8192;                           // edges per chunk
constexpr int NCH      = (N_EDGES + CH_E - 1) / CH_E;    // 196
constexpr int CAP1     = 160;  // per (bin,chunk): mean 84, +8.3 sigma
constexpr int CAP2     = 18432; // per bin: mean 16384, +16 sigma

// bf16 helpers (RNE)
static __device__ __forceinline__ unsigned short f2bf(float f) {
    unsigned u = __float_as_uint(f);
    u += 0x7FFFu + ((u >> 16) & 1u);
    return (unsigned short)(u >> 16);
}
static __device__ __forceinline__ float b2f(unsigned short h) {
    return __uint_as_float(((unsigned)h) << 16);
}

// ---------------- graph boundaries (batch is sorted) ----------------

__global__ void k_gbounds(const int* __restrict__ batch, int* __restrict__ gstart) {
    int i = blockIdx.x * blockDim.x + threadIdx.x;
    if (i >= N_NODES) return;
    int b = batch[i];
    if (i == 0) {
        for (int g = 0; g <= b; ++g) gstart[g] = 0;
    } else {
        int bp = batch[i - 1];
        for (int g = bp + 1; g <= b; ++g) gstart[g] = i;
    }
    if (i == N_NODES - 1) {
        for (int g = b + 1; g <= NUM_GRAPHS; ++g) gstart[g] = N_NODES;
    }
}

// ---------------- CSR build pass 1: LDS-binned, full-line flush ----------------
// Block = one chunk of CH_E edges. Append packed (src<<10 | dst&1023) into LDS
// bins (LDS atomics only), then flush each bin as a contiguous run to
// slab[bin][chunk][CAP1]. All global writes are sequential -> no partial-line
// writeback amplification, no global atomics.

__global__ __launch_bounds__(256) void k_p1(const int* __restrict__ src,
                                            const int* __restrict__ dst,
                                            unsigned* __restrict__ slab,
                                            int* __restrict__ gcnt) {
    __shared__ unsigned bl[NBIN * CAP1];   // 62.7 KB
    __shared__ int c1[NBIN];

    const int ch = blockIdx.x;
    const int t  = threadIdx.x;
    for (int i = t; i < NBIN; i += 256) c1[i] = 0;
    __syncthreads();

    const int e0 = ch * CH_E;
    const int e1 = (e0 + CH_E < N_EDGES) ? e0 + CH_E : N_EDGES;
    for (int e = e0 + t; e < e1; e += 256) {
        int d = dst[e];
        int s = src[e];
        int b = d >> BINSHIFT;
        int pos = atomicAdd(&c1[b], 1);
        if (pos < CAP1)
            bl[b * CAP1 + pos] = ((unsigned)s << BINSHIFT) | (unsigned)(d & (BINSZ - 1));
    }
    __syncthreads();

    // flush: wave w handles bins w, w+4, ... (coalesced within wave)
    const int wv = t >> 6, ln = t & 63;
    for (int b = wv; b < NBIN; b += 4) {
        int n = c1[b]; n = n < CAP1 ? n : CAP1;
        unsigned* sp = &slab[((size_t)b * NCH + ch) * CAP1];
        for (int i = ln; i < n; i += 64) sp[i] = bl[b * CAP1 + i];
        if (ln == 0) gcnt[b * NCH + ch] = n;
    }
}

// ---------------- bin base scan (tiny) ----------------

__global__ void k_binscan(const int* __restrict__ gcnt, int* __restrict__ binbase) {
    __shared__ int T[NBIN];
    int t = threadIdx.x;
    if (t < NBIN) {
        int s = 0;
        for (int c = 0; c < NCH; ++c) s += gcnt[t * NCH + c];
        T[t] = s;
    }
    __syncthreads();
    if (t == 0) {
        int run = 0;
        for (int b = 0; b < NBIN; ++b) { binbase[b] = run; run += T[b]; }
        binbase[NBIN] = run;
    }
}

// ---------------- CSR build pass 2: per-bin finalize ----------------
// One block per bin (1024 nodes). Load slab runs -> LDS, per-node histogram,
// LDS scan, scatter into the bin's private csr_src window (single block ->
// single L2, lines merge), emit offs + dinv.

__global__ __launch_bounds__(256) void k_p2(const unsigned* __restrict__ slab,
                                            const int* __restrict__ gcnt,
                                            const int* __restrict__ binbase,
                                            int* __restrict__ csr_src,
                                            int* __restrict__ offs,
                                            float* __restrict__ dinv) {
    __shared__ unsigned eb[CAP2];          // 72 KB
    __shared__ int cnt2[BINSZ];
    __shared__ int off2[BINSZ];
    __shared__ int cur[BINSZ];
    __shared__ int choff[NCH + 1];
    __shared__ int tsum[256];

    const int bin = blockIdx.x;
    const int t   = threadIdx.x;

    if (t == 0) {
        int r = 0;
        for (int c = 0; c < NCH; ++c) { choff[c] = r; r += gcnt[bin * NCH + c]; }
        choff[NCH] = r;
    }
    for (int i = t; i < BINSZ; i += 256) { cnt2[i] = 0; cur[i] = 0; }
    __syncthreads();
    int total = choff[NCH]; total = total < CAP2 ? total : CAP2;

    // gather slab runs + histogram
    for (int c = 0; c < NCH; ++c) {
        int o = choff[c];
        int n = choff[c + 1] - o;
        const unsigned* sp = &slab[((size_t)bin * NCH + c) * CAP1];
        for (int i = t; i < n; i += 256) {
            int idx = o + i;
            if (idx < CAP2) {
                unsigned v = sp[i];
                eb[idx] = v;
                atomicAdd(&cnt2[v & (BINSZ - 1)], 1);
            }
        }
    }
    __syncthreads();

    // exclusive scan of cnt2[1024]
    {
        int base4 = t * 4;
        int loc[4], s = 0;
        #pragma unroll
        for (int j = 0; j < 4; ++j) { loc[j] = s; s += cnt2[base4 + j]; }
        tsum[t] = s;
        __syncthreads();
        for (int off = 1; off < 256; off <<= 1) {
            int add = (t >= off) ? tsum[t - off] : 0;
            __syncthreads();
            tsum[t] += add;
            __syncthreads();
        }
        int excl = tsum[t] - s;
        #pragma unroll
        for (int j = 0; j < 4; ++j) off2[base4 + j] = excl + loc[j];
    }
    __syncthreads();

    const int base  = binbase[bin];
    const int node0 = bin << BINSHIFT;
    for (int i = t; i < BINSZ; i += 256) {
        int node = node0 + i;
        if (node < N_NODES) {
            offs[node] = base + off2[i];
            dinv[node] = rsqrtf((float)(cnt2[i] + 1));   // +1 self-loop
        }
    }
    if (bin == NBIN - 1 && t == 0) offs[N_NODES] = base + total;

    // scatter into the bin's csr window (64 KB, single-L2 -> merges)
    for (int i = t; i < total; i += 256) {
        unsigned v = eb[i];
        int lo = v & (BINSZ - 1);
        int p = atomicAdd(&cur[lo], 1);
        csr_src[base + off2[lo] + p] = (int)(v >> BINSHIFT);
    }
}

// ---------------- dense GEMM: Hb = dinv ⊙ (X @ W) in bf16 ----------------

__global__ __launch_bounds__(256) void k_gemm(const float* __restrict__ X,
                                              const float* __restrict__ W,
                                              const float* __restrict__ dinv,
                                              unsigned short* __restrict__ Hb) {
    __shared__ float Xl[128 * PADK];
    __shared__ float Wl[128 * 128];

    const int t    = threadIdx.x;
    const int row0 = blockIdx.x * 128;
    const int kk   = t >> 5;           // 0..7
    const int c4   = (t & 31) * 4;     // 0..124

    #pragma unroll
    for (int p = 0; p < 16; ++p) {
        int r = kk + p * 8;
        float4 wv = *(const float4*)&W[r * HIDDEN + c4];
        *(float4*)&Wl[r * HIDDEN + c4] = wv;
        int rg = row0 + r;
        rg = rg < N_NODES ? rg : N_NODES - 1;   // clamp (tail block)
        float4 xv = *(const float4*)&X[(size_t)rg * HIDDEN + c4];
        *(float4*)&Xl[r * PADK + c4] = xv;
    }
    __syncthreads();

    const int trow = t >> 4;   // 0..15
    const int tcol = t & 15;   // 0..15

    float4 accA[8], accB[8];
    #pragma unroll
    for (int r = 0; r < 8; ++r) {
        accA[r] = make_float4(0.f, 0.f, 0.f, 0.f);
        accB[r] = make_float4(0.f, 0.f, 0.f, 0.f);
    }

    #pragma unroll 4
    for (int k = 0; k < HIDDEN; ++k) {
        float4 wa = *(const float4*)&Wl[k * HIDDEN + tcol * 4];
        float4 wb = *(const float4*)&Wl[k * HIDDEN + 64 + tcol * 4];
        float xs[8];
        #pragma unroll
        for (int r = 0; r < 4; ++r) {
            xs[r]     = Xl[(trow * 4 + r) * PADK + k];
            xs[r + 4] = Xl[(64 + trow * 4 + r) * PADK + k];
        }
        #pragma unroll
        for (int r = 0; r < 8; ++r) {
            accA[r].x += xs[r] * wa.x; accA[r].y += xs[r] * wa.y;
            accA[r].z += xs[r] * wa.z; accA[r].w += xs[r] * wa.w;
            accB[r].x += xs[r] * wb.x; accB[r].y += xs[r] * wb.y;
            accB[r].z += xs[r] * wb.z; accB[r].w += xs[r] * wb.w;
        }
    }

    #pragma unroll
    for (int r = 0; r < 8; ++r) {
        int rloc = (r < 4) ? (trow * 4 + r) : (64 + trow * 4 + (r - 4));
        int row  = row0 + rloc;
        if (row < N_NODES) {
            float di = dinv[row];
            ushort4 oa, ob;
            oa.x = f2bf(accA[r].x * di); oa.y = f2bf(accA[r].y * di);
            oa.z = f2bf(accA[r].z * di); oa.w = f2bf(accA[r].w * di);
            ob.x = f2bf(accB[r].x * di); ob.y = f2bf(accB[r].y * di);
            ob.z = f2bf(accB[r].z * di); ob.w = f2bf(accB[r].w * di);
            *(ushort4*)&Hb[(size_t)row * HIDDEN + tcol * 4]      = oa;
            *(ushort4*)&Hb[(size_t)row * HIDDEN + 64 + tcol * 4] = ob;
        }
    }
}

// ---------------- fused aggregation over pre-scaled bf16 rows ----------------

template <bool OUT_BF16, bool BIAS, bool RELU, bool OUTSCALE>
__global__ __launch_bounds__(256) void k_aggregate(const unsigned short* __restrict__ Hb,
                                                   const int* __restrict__ offs,
                                                   const int* __restrict__ csr_src,
                                                   const float* __restrict__ dinv,
                                                   const float* __restrict__ bias,
                                                   void* __restrict__ outv) {
    int g    = threadIdx.x >> 5;       // node-in-block 0..7
    int lane = threadIdx.x & 31;
    int node = blockIdx.x * 8 + g;
    if (node >= N_NODES) return;
    int c4 = lane * 4;

    float di = dinv[node];
    ushort4 sv = *(const ushort4*)&Hb[(size_t)node * HIDDEN + c4];
    float4 acc;
    acc.x = b2f(sv.x); acc.y = b2f(sv.y); acc.z = b2f(sv.z); acc.w = b2f(sv.w);

    int j0 = offs[node], j1 = offs[node + 1];
    #pragma unroll 4
    for (int j = j0; j < j1; ++j) {
        int s = csr_src[j];
        ushort4 v = *(const ushort4*)&Hb[(size_t)s * HIDDEN + c4];
        acc.x += b2f(v.x); acc.y += b2f(v.y);
        acc.z += b2f(v.z); acc.w += b2f(v.w);
    }

    acc.x *= di; acc.y *= di; acc.z *= di; acc.w *= di;
    if (BIAS) {
        float4 bv = *(const float4*)&bias[c4];
        acc.x += bv.x; acc.y += bv.y; acc.z += bv.z; acc.w += bv.w;
    }
    if (RELU) {
        acc.x = fmaxf(acc.x, 0.f); acc.y = fmaxf(acc.y, 0.f);
        acc.z = fmaxf(acc.z, 0.f); acc.w = fmaxf(acc.w, 0.f);
    }
    if (OUTSCALE) {
        acc.x *= di; acc.y *= di; acc.z *= di; acc.w *= di;
    }
    if (OUT_BF16) {
        ushort4 o;
        o.x = f2bf(acc.x); o.y = f2bf(acc.y); o.z = f2bf(acc.z); o.w = f2bf(acc.w);
        *(ushort4*)&((unsigned short*)outv)[(size_t)node * HIDDEN + c4] = o;
    } else {
        *(float4*)&((float*)outv)[(size_t)node * HIDDEN + c4] = acc;
    }
}

// ---------------- pooling: segmented reduction, no atomics ----------------

__global__ __launch_bounds__(256) void k_pool2(const float* __restrict__ X,
                                               const int* __restrict__ gstart,
                                               float* __restrict__ part) {
    int g  = blockIdx.x;
    int ch = blockIdx.y;
    int start = gstart[g], end = gstart[g + 1];
    int len = end - start;
    int r0 = start + (int)((long long)len * ch / POOL_CHUNKS);
    int r1 = start + (int)((long long)len * (ch + 1) / POOL_CHUNKS);

    int rp = threadIdx.x >> 5;         // 0..7 rows in parallel
    int c4 = (threadIdx.x & 31) * 4;

    float4 acc = make_float4(0.f, 0.f, 0.f, 0.f);
    for (int r = r0 + rp; r < r1; r += 8) {
        float4 v = *(const float4*)&X[(size_t)r * HIDDEN + c4];
        acc.x += v.x; acc.y += v.y; acc.z += v.z; acc.w += v.w;
    }

    __shared__ float4 sh[256];
    sh[threadIdx.x] = acc;
    __syncthreads();
    #pragma unroll
    for (int off = 4; off >= 1; off >>= 1) {
        if (rp < off) {
            float4 o = sh[(rp + off) * 32 + (threadIdx.x & 31)];
            float4 m = sh[threadIdx.x];
            m.x += o.x; m.y += o.y; m.z += o.z; m.w += o.w;
            sh[threadIdx.x] = m;
        }
        __syncthreads();
    }
    if (rp == 0) {
        float4 v = sh[threadIdx.x];
        *(float4*)&part[((size_t)g * POOL_CHUNKS + ch) * HIDDEN + c4] = v;
    }
}

// ---------------- final: out = ((Σpart/cnt) @ W2 + b2) @ linW + linb ----------------

__global__ void k_final(const float* __restrict__ part, const int* __restrict__ gstart,
                        const float* __restrict__ W2, const float* __restrict__ b2,
                        const float* __restrict__ linW, const float* __restrict__ linb,
                        float* __restrict__ out) {
    __shared__ float m[HIDDEN];
    __shared__ float t[HIDDEN];
    int g = blockIdx.x;
    int c = threadIdx.x;
    float s = 0.f;
    #pragma unroll
    for (int ch = 0; ch < POOL_CHUNKS; ++ch)
        s += part[((size_t)g * POOL_CHUNKS + ch) * HIDDEN + c];
    float cnt = fmaxf((float)(gstart[g + 1] - gstart[g]), 1.0f);
    m[c] = s / cnt;
    __syncthreads();
    float acc = b2[c];
    #pragma unroll 4
    for (int k = 0; k < HIDDEN; ++k) acc += m[k] * W2[k * HIDDEN + c];
    t[c] = acc;
    __syncthreads();
    if (c < 16) {
        float o = linb[c];
        #pragma unroll 4
        for (int k = 0; k < HIDDEN; ++k) o += t[k] * linW[k * 16 + c];
        out[g * 16 + c] = o;
    }
}

// ---------------- launch ----------------

extern "C" void kernel_launch(void* const* d_in, const int* in_sizes, int n_in,
                              void* d_out, int out_size, void* d_ws, size_t ws_size,
                              hipStream_t stream) {
    const float* x     = (const float*)d_in[0];
    const int*   edge  = (const int*)d_in[1];   // [2, E] flat
    const int*   batch = (const int*)d_in[2];
    const float* Ws    = (const float*)d_in[3]; // [3,128,128]
    const float* bs    = (const float*)d_in[4]; // [3,128]
    const float* linW  = (const float*)d_in[5]; // [128,16]
    const float* linb  = (const float*)d_in[6]; // [16]
    float* out = (float*)d_out;

    const int* src = edge;
    const int* dst = edge + N_EDGES;

    // workspace layout
    float* bufA = (float*)d_ws;                       // N*128 fp32 (x1, then x3)
    unsigned* slab = (unsigned*)bufA;                 // NBIN*NCH*CAP1 u32 (12.3MB) — CSR-build
                                                      // scratch; dead before agg1 writes bufA
    float* bufBreg = bufA + (size_t)N_NODES * HIDDEN; // N*128 fp32-sized region, carved:
    unsigned short* hb  = (unsigned short*)bufBreg;                            // N*128 bf16
    unsigned short* x2b = (unsigned short*)bufBreg + (size_t)N_NODES * HIDDEN; // N*128 bf16
    float* dinv = bufBreg + (size_t)N_NODES * HIDDEN; // N
    float* part = dinv + N_NODES;                     // 64*16*128
    int* offs    = (int*)(part + NUM_GRAPHS * POOL_CHUNKS * HIDDEN); // N+1
    int* csr_src = offs + N_NODES + 1;                // E
    int* gstart  = csr_src + N_EDGES;                 // NUM_GRAPHS+1
    int* gcnt    = gstart + NUM_GRAPHS + 1;           // NBIN*NCH
    int* binbase = gcnt + NBIN * NCH;                 // NBIN+1

    const int NB_N    = (N_NODES + 255) / 256;   // 391
    const int NB_ROW  = N_NODES / 8;             // 12500
    const int NB_GEMM = (N_NODES + 127) / 128;   // 782

    // CSR build (also produces offs, dinv) — LDS-staged, no global atomics
    k_p1<<<NCH, 256, 0, stream>>>(src, dst, slab, gcnt);
    k_binscan<<<1, 128, 0, stream>>>(gcnt, binbase);
    k_p2<<<NBIN, 256, 0, stream>>>(slab, gcnt, binbase, csr_src, offs, dinv);
    k_gbounds<<<NB_N, 256, 0, stream>>>(batch, gstart);

    // layer 0: hb = dinv ⊙ (x@W0) ; x1 = relu(dinv*(Σ hb) + b0)         [fp32 out]
    k_gemm<<<NB_GEMM, 256, 0, stream>>>(x, Ws, dinv, hb);
    k_aggregate<false, true, true, false><<<NB_ROW, 256, 0, stream>>>(hb, offs, csr_src, dinv, bs, bufA);

    // layer 1: hb = dinv ⊙ (x1@W1) ; x2' = dinv*relu(dinv*(Σ hb) + b1)  [bf16 out, pre-scaled]
    k_gemm<<<NB_GEMM, 256, 0, stream>>>(bufA, Ws + HIDDEN * HIDDEN, dinv, hb);
    k_aggregate<true, true, true, true><<<NB_ROW, 256, 0, stream>>>(hb, offs, csr_src, dinv, bs + HIDDEN, x2b);

    // layer 2 (algebraic trick): x3 = dinv*(Σ x2') ; pool ; tiny GEMMs in k_final
    k_aggregate<false, false, false, false><<<NB_ROW, 256, 0, stream>>>(x2b, offs, csr_src, dinv, nullptr, bufA);
    k_pool2<<<dim3(NUM_GRAPHS, POOL_CHUNKS), 256, 0, stream>>>(bufA, gstart, part);

    k_final<<<NUM_GRAPHS, HIDDEN, 0, stream>>>(part, gstart,
                                               Ws + 2 * HIDDEN * HIDDEN, bs + 2 * HIDDEN,
                                               linW, linb, out);
}

// Round 8
// 411.587 us; speedup vs baseline: 1.1683x; 1.1547x over previous
//
#include <hip/hip_runtime.h>
#include <math.h>

#define N_NODES    100000
#define N_EDGES    1600000
#define HIDDEN     128
#define NUM_GRAPHS 64

constexpr int POOL_CHUNKS = 16;
constexpr int PADK        = 132;

// ---- two-level LDS-staged CSR build ----
constexpr int BINSHIFT = 10;
constexpr int BINSZ    = 1 << BINSHIFT;                  // 1024 nodes per bin
constexpr int NBIN     = (N_NODES + BINSZ - 1) / BINSZ;  // 98
constexpr int CH_E     = 8192;                           // edges per chunk
constexpr int NCH      = (N_EDGES + CH_E - 1) / CH_E;    // 196
constexpr int CAP1     = 160;  // per (bin,chunk): mean 84, +8.3 sigma
constexpr int CAP2     = 18432; // per bin: mean 16384, +16 sigma

// bf16 helpers (RNE)
static __device__ __forceinline__ unsigned short f2bf(float f) {
    unsigned u = __float_as_uint(f);
    u += 0x7FFFu + ((u >> 16) & 1u);
    return (unsigned short)(u >> 16);
}
static __device__ __forceinline__ float b2f(unsigned short h) {
    return __uint_as_float(((unsigned)h) << 16);
}

// ---------------- graph boundaries (batch is sorted) ----------------

__global__ void k_gbounds(const int* __restrict__ batch, int* __restrict__ gstart) {
    int i = blockIdx.x * blockDim.x + threadIdx.x;
    if (i >= N_NODES) return;
    int b = batch[i];
    if (i == 0) {
        for (int g = 0; g <= b; ++g) gstart[g] = 0;
    } else {
        int bp = batch[i - 1];
        for (int g = bp + 1; g <= b; ++g) gstart[g] = i;
    }
    if (i == N_NODES - 1) {
        for (int g = b + 1; g <= NUM_GRAPHS; ++g) gstart[g] = N_NODES;
    }
}

// ---------------- CSR build pass 1: LDS-binned, full-line flush ----------------

__global__ __launch_bounds__(256) void k_p1(const int* __restrict__ src,
                                            const int* __restrict__ dst,
                                            unsigned* __restrict__ slab,
                                            int* __restrict__ gcnt) {
    __shared__ unsigned bl[NBIN * CAP1];   // 62.7 KB
    __shared__ int c1[NBIN];

    const int ch = blockIdx.x;
    const int t  = threadIdx.x;
    for (int i = t; i < NBIN; i += 256) c1[i] = 0;
    __syncthreads();

    const int e0 = ch * CH_E;
    const int e1 = (e0 + CH_E < N_EDGES) ? e0 + CH_E : N_EDGES;
    for (int e = e0 + t; e < e1; e += 256) {
        int d = dst[e];
        int s = src[e];
        int b = d >> BINSHIFT;
        int pos = atomicAdd(&c1[b], 1);
        if (pos < CAP1)
            bl[b * CAP1 + pos] = ((unsigned)s << BINSHIFT) | (unsigned)(d & (BINSZ - 1));
    }
    __syncthreads();

    // flush: wave w handles bins w, w+4, ... (coalesced within wave)
    const int wv = t >> 6, ln = t & 63;
    for (int b = wv; b < NBIN; b += 4) {
        int n = c1[b]; n = n < CAP1 ? n : CAP1;
        unsigned* sp = &slab[((size_t)b * NCH + ch) * CAP1];
        for (int i = ln; i < n; i += 64) sp[i] = bl[b * CAP1 + i];
        if (ln == 0) gcnt[b * NCH + ch] = n;
    }
}

// ---------------- bin base scan (tiny) ----------------

__global__ void k_binscan(const int* __restrict__ gcnt, int* __restrict__ binbase) {
    __shared__ int T[NBIN];
    int t = threadIdx.x;
    if (t < NBIN) {
        int s = 0;
        for (int c = 0; c < NCH; ++c) s += gcnt[t * NCH + c];
        T[t] = s;
    }
    __syncthreads();
    if (t == 0) {
        int run = 0;
        for (int b = 0; b < NBIN; ++b) { binbase[b] = run; run += T[b]; }
        binbase[NBIN] = run;
    }
}

// ---------------- CSR build pass 2: per-bin finalize, latency-parallel ----------------
// 1024 threads (16 waves). choff via parallel scan; gather with 16 chunks in
// flight (wave w -> chunks w, w+16, ...); 1024-wide node scan; LDS scatter into
// the bin's private 64 KB csr window.

__global__ __launch_bounds__(1024) void k_p2(const unsigned* __restrict__ slab,
                                             const int* __restrict__ gcnt,
                                             const int* __restrict__ binbase,
                                             int* __restrict__ csr_src,
                                             int* __restrict__ offs,
                                             float* __restrict__ dinv) {
    __shared__ unsigned eb[CAP2];          // 72 KB
    __shared__ int cnt2[BINSZ];
    __shared__ int off2[BINSZ];
    __shared__ int cur[BINSZ];
    __shared__ int choff[NCH + 1];
    __shared__ int csc[256];

    const int bin = blockIdx.x;
    const int t   = threadIdx.x;

    cnt2[t] = 0; cur[t] = 0;               // blockDim == BINSZ == 1024
    if (t < 256) csc[t] = (t < NCH) ? gcnt[bin * NCH + t] : 0;
    __syncthreads();

    // inclusive scan over 256 chunk counts
    for (int off = 1; off < 256; off <<= 1) {
        int add = 0;
        if (t < 256 && t >= off) add = csc[t - off];
        __syncthreads();
        if (t < 256) csc[t] += add;
        __syncthreads();
    }
    if (t < NCH) {
        int v = gcnt[bin * NCH + t];
        choff[t] = csc[t] - v;             // exclusive
        if (t == NCH - 1) choff[NCH] = csc[t];
    }
    __syncthreads();
    int total = choff[NCH]; total = total < CAP2 ? total : CAP2;

    // gather slab runs + histogram: wave w -> chunks w, w+16, ...
    const int wv = t >> 6, ln = t & 63;
    for (int c = wv; c < NCH; c += 16) {
        int o = choff[c];
        int n = choff[c + 1] - o;
        const unsigned* sp = &slab[((size_t)bin * NCH + c) * CAP1];
        for (int i = ln; i < n; i += 64) {
            int idx = o + i;
            if (idx < CAP2) {
                unsigned v = sp[i];
                eb[idx] = v;
                atomicAdd(&cnt2[v & (BINSZ - 1)], 1);
            }
        }
    }
    __syncthreads();

    // exclusive scan over cnt2[1024], one node per thread
    int mycnt = cnt2[t];
    off2[t] = mycnt;
    __syncthreads();
    for (int off = 1; off < BINSZ; off <<= 1) {
        int add = (t >= off) ? off2[t - off] : 0;
        __syncthreads();
        off2[t] += add;
        __syncthreads();
    }
    int excl = off2[t] - mycnt;
    __syncthreads();
    off2[t] = excl;
    __syncthreads();

    const int base  = binbase[bin];
    const int node0 = bin << BINSHIFT;
    int node = node0 + t;
    if (node < N_NODES) {
        offs[node] = base + excl;
        dinv[node] = rsqrtf((float)(mycnt + 1));   // +1 self-loop
    }
    if (bin == NBIN - 1 && t == 0) offs[N_NODES] = base + total;
    __syncthreads();

    // scatter into the bin's csr window (64 KB, single block -> merges in L2)
    for (int i = t; i < total; i += 1024) {
        unsigned v = eb[i];
        int lo = v & (BINSZ - 1);
        int p = atomicAdd(&cur[lo], 1);
        csr_src[base + off2[lo] + p] = (int)(v >> BINSHIFT);
    }
}

// ---------------- dense GEMM: Hb = dinv ⊙ (X @ W) in bf16 ----------------

__global__ __launch_bounds__(256) void k_gemm(const float* __restrict__ X,
                                              const float* __restrict__ W,
                                              const float* __restrict__ dinv,
                                              unsigned short* __restrict__ Hb) {
    __shared__ float Xl[128 * PADK];
    __shared__ float Wl[128 * 128];

    const int t    = threadIdx.x;
    const int row0 = blockIdx.x * 128;
    const int kk   = t >> 5;           // 0..7
    const int c4   = (t & 31) * 4;     // 0..124

    #pragma unroll
    for (int p = 0; p < 16; ++p) {
        int r = kk + p * 8;
        float4 wv = *(const float4*)&W[r * HIDDEN + c4];
        *(float4*)&Wl[r * HIDDEN + c4] = wv;
        int rg = row0 + r;
        rg = rg < N_NODES ? rg : N_NODES - 1;   // clamp (tail block)
        float4 xv = *(const float4*)&X[(size_t)rg * HIDDEN + c4];
        *(float4*)&Xl[r * PADK + c4] = xv;
    }
    __syncthreads();

    const int trow = t >> 4;   // 0..15
    const int tcol = t & 15;   // 0..15

    float4 accA[8], accB[8];
    #pragma unroll
    for (int r = 0; r < 8; ++r) {
        accA[r] = make_float4(0.f, 0.f, 0.f, 0.f);
        accB[r] = make_float4(0.f, 0.f, 0.f, 0.f);
    }

    #pragma unroll 4
    for (int k = 0; k < HIDDEN; ++k) {
        float4 wa = *(const float4*)&Wl[k * HIDDEN + tcol * 4];
        float4 wb = *(const float4*)&Wl[k * HIDDEN + 64 + tcol * 4];
        float xs[8];
        #pragma unroll
        for (int r = 0; r < 4; ++r) {
            xs[r]     = Xl[(trow * 4 + r) * PADK + k];
            xs[r + 4] = Xl[(64 + trow * 4 + r) * PADK + k];
        }
        #pragma unroll
        for (int r = 0; r < 8; ++r) {
            accA[r].x += xs[r] * wa.x; accA[r].y += xs[r] * wa.y;
            accA[r].z += xs[r] * wa.z; accA[r].w += xs[r] * wa.w;
            accB[r].x += xs[r] * wb.x; accB[r].y += xs[r] * wb.y;
            accB[r].z += xs[r] * wb.z; accB[r].w += xs[r] * wb.w;
        }
    }

    #pragma unroll
    for (int r = 0; r < 8; ++r) {
        int rloc = (r < 4) ? (trow * 4 + r) : (64 + trow * 4 + (r - 4));
        int row  = row0 + rloc;
        if (row < N_NODES) {
            float di = dinv[row];
            ushort4 oa, ob;
            oa.x = f2bf(accA[r].x * di); oa.y = f2bf(accA[r].y * di);
            oa.z = f2bf(accA[r].z * di); oa.w = f2bf(accA[r].w * di);
            ob.x = f2bf(accB[r].x * di); ob.y = f2bf(accB[r].y * di);
            ob.z = f2bf(accB[r].z * di); ob.w = f2bf(accB[r].w * di);
            *(ushort4*)&Hb[(size_t)row * HIDDEN + tcol * 4]      = oa;
            *(ushort4*)&Hb[(size_t)row * HIDDEN + 64 + tcol * 4] = ob;
        }
    }
}

// ---------------- fused aggregation over pre-scaled bf16 rows ----------------

template <bool OUT_BF16, bool BIAS, bool RELU, bool OUTSCALE>
__global__ __launch_bounds__(256) void k_aggregate(const unsigned short* __restrict__ Hb,
                                                   const int* __restrict__ offs,
                                                   const int* __restrict__ csr_src,
                                                   const float* __restrict__ dinv,
                                                   const float* __restrict__ bias,
                                                   void* __restrict__ outv) {
    int g    = threadIdx.x >> 5;       // node-in-block 0..7
    int lane = threadIdx.x & 31;
    int node = blockIdx.x * 8 + g;
    if (node >= N_NODES) return;
    int c4 = lane * 4;

    float di = dinv[node];
    ushort4 sv = *(const ushort4*)&Hb[(size_t)node * HIDDEN + c4];
    float4 acc;
    acc.x = b2f(sv.x); acc.y = b2f(sv.y); acc.z = b2f(sv.z); acc.w = b2f(sv.w);

    int j0 = offs[node], j1 = offs[node + 1];
    #pragma unroll 4
    for (int j = j0; j < j1; ++j) {
        int s = csr_src[j];
        ushort4 v = *(const ushort4*)&Hb[(size_t)s * HIDDEN + c4];
        acc.x += b2f(v.x); acc.y += b2f(v.y);
        acc.z += b2f(v.z); acc.w += b2f(v.w);
    }

    acc.x *= di; acc.y *= di; acc.z *= di; acc.w *= di;
    if (BIAS) {
        float4 bv = *(const float4*)&bias[c4];
        acc.x += bv.x; acc.y += bv.y; acc.z += bv.z; acc.w += bv.w;
    }
    if (RELU) {
        acc.x = fmaxf(acc.x, 0.f); acc.y = fmaxf(acc.y, 0.f);
        acc.z = fmaxf(acc.z, 0.f); acc.w = fmaxf(acc.w, 0.f);
    }
    if (OUTSCALE) {
        acc.x *= di; acc.y *= di; acc.z *= di; acc.w *= di;
    }
    if (OUT_BF16) {
        ushort4 o;
        o.x = f2bf(acc.x); o.y = f2bf(acc.y); o.z = f2bf(acc.z); o.w = f2bf(acc.w);
        *(ushort4*)&((unsigned short*)outv)[(size_t)node * HIDDEN + c4] = o;
    } else {
        *(float4*)&((float*)outv)[(size_t)node * HIDDEN + c4] = acc;
    }
}

// ---------------- pooling: segmented reduction, no atomics ----------------

__global__ __launch_bounds__(256) void k_pool2(const float* __restrict__ X,
                                               const int* __restrict__ gstart,
                                               float* __restrict__ part) {
    int g  = blockIdx.x;
    int ch = blockIdx.y;
    int start = gstart[g], end = gstart[g + 1];
    int len = end - start;
    int r0 = start + (int)((long long)len * ch / POOL_CHUNKS);
    int r1 = start + (int)((long long)len * (ch + 1) / POOL_CHUNKS);

    int rp = threadIdx.x >> 5;         // 0..7 rows in parallel
    int c4 = (threadIdx.x & 31) * 4;

    float4 acc = make_float4(0.f, 0.f, 0.f, 0.f);
    for (int r = r0 + rp; r < r1; r += 8) {
        float4 v = *(const float4*)&X[(size_t)r * HIDDEN + c4];
        acc.x += v.x; acc.y += v.y; acc.z += v.z; acc.w += v.w;
    }

    __shared__ float4 sh[256];
    sh[threadIdx.x] = acc;
    __syncthreads();
    #pragma unroll
    for (int off = 4; off >= 1; off >>= 1) {
        if (rp < off) {
            float4 o = sh[(rp + off) * 32 + (threadIdx.x & 31)];
            float4 m = sh[threadIdx.x];
            m.x += o.x; m.y += o.y; m.z += o.z; m.w += o.w;
            sh[threadIdx.x] = m;
        }
        __syncthreads();
    }
    if (rp == 0) {
        float4 v = sh[threadIdx.x];
        *(float4*)&part[((size_t)g * POOL_CHUNKS + ch) * HIDDEN + c4] = v;
    }
}

// ---------------- final: out = ((Σpart/cnt) @ W2 + b2) @ linW + linb ----------------

__global__ void k_final(const float* __restrict__ part, const int* __restrict__ gstart,
                        const float* __restrict__ W2, const float* __restrict__ b2,
                        const float* __restrict__ linW, const float* __restrict__ linb,
                        float* __restrict__ out) {
    __shared__ float m[HIDDEN];
    __shared__ float t[HIDDEN];
    int g = blockIdx.x;
    int c = threadIdx.x;
    float s = 0.f;
    #pragma unroll
    for (int ch = 0; ch < POOL_CHUNKS; ++ch)
        s += part[((size_t)g * POOL_CHUNKS + ch) * HIDDEN + c];
    float cnt = fmaxf((float)(gstart[g + 1] - gstart[g]), 1.0f);
    m[c] = s / cnt;
    __syncthreads();
    float acc = b2[c];
    #pragma unroll 4
    for (int k = 0; k < HIDDEN; ++k) acc += m[k] * W2[k * HIDDEN + c];
    t[c] = acc;
    __syncthreads();
    if (c < 16) {
        float o = linb[c];
        #pragma unroll 4
        for (int k = 0; k < HIDDEN; ++k) o += t[k] * linW[k * 16 + c];
        out[g * 16 + c] = o;
    }
}

// ---------------- launch ----------------

extern "C" void kernel_launch(void* const* d_in, const int* in_sizes, int n_in,
                              void* d_out, int out_size, void* d_ws, size_t ws_size,
                              hipStream_t stream) {
    const float* x     = (const float*)d_in[0];
    const int*   edge  = (const int*)d_in[1];   // [2, E] flat
    const int*   batch = (const int*)d_in[2];
    const float* Ws    = (const float*)d_in[3]; // [3,128,128]
    const float* bs    = (const float*)d_in[4]; // [3,128]
    const float* linW  = (const float*)d_in[5]; // [128,16]
    const float* linb  = (const float*)d_in[6]; // [16]
    float* out = (float*)d_out;

    const int* src = edge;
    const int* dst = edge + N_EDGES;

    // workspace layout
    float* bufA = (float*)d_ws;                       // N*128 fp32 (x1, then x3)
    unsigned* slab = (unsigned*)bufA;                 // NBIN*NCH*CAP1 u32 (12.3MB) — CSR-build
                                                      // scratch; dead before agg1 writes bufA
    float* bufBreg = bufA + (size_t)N_NODES * HIDDEN; // N*128 fp32-sized region, carved:
    unsigned short* hb  = (unsigned short*)bufBreg;                            // N*128 bf16
    unsigned short* x2b = (unsigned short*)bufBreg + (size_t)N_NODES * HIDDEN; // N*128 bf16
    float* dinv = bufBreg + (size_t)N_NODES * HIDDEN; // N
    float* part = dinv + N_NODES;                     // 64*16*128
    int* offs    = (int*)(part + NUM_GRAPHS * POOL_CHUNKS * HIDDEN); // N+1
    int* csr_src = offs + N_NODES + 1;                // E
    int* gstart  = csr_src + N_EDGES;                 // NUM_GRAPHS+1
    int* gcnt    = gstart + NUM_GRAPHS + 1;           // NBIN*NCH
    int* binbase = gcnt + NBIN * NCH;                 // NBIN+1

    const int NB_N    = (N_NODES + 255) / 256;   // 391
    const int NB_ROW  = N_NODES / 8;             // 12500
    const int NB_GEMM = (N_NODES + 127) / 128;   // 782

    // CSR build (also produces offs, dinv) — LDS-staged, no global atomics
    k_p1<<<NCH, 256, 0, stream>>>(src, dst, slab, gcnt);
    k_binscan<<<1, 128, 0, stream>>>(gcnt, binbase);
    k_p2<<<NBIN, 1024, 0, stream>>>(slab, gcnt, binbase, csr_src, offs, dinv);
    k_gbounds<<<NB_N, 256, 0, stream>>>(batch, gstart);

    // layer 0: hb = dinv ⊙ (x@W0) ; x1 = relu(dinv*(Σ hb) + b0)         [fp32 out]
    k_gemm<<<NB_GEMM, 256, 0, stream>>>(x, Ws, dinv, hb);
    k_aggregate<false, true, true, false><<<NB_ROW, 256, 0, stream>>>(hb, offs, csr_src, dinv, bs, bufA);

    // layer 1: hb = dinv ⊙ (x1@W1) ; x2' = dinv*relu(dinv*(Σ hb) + b1)  [bf16 out, pre-scaled]
    k_gemm<<<NB_GEMM, 256, 0, stream>>>(bufA, Ws + HIDDEN * HIDDEN, dinv, hb);
    k_aggregate<true, true, true, true><<<NB_ROW, 256, 0, stream>>>(hb, offs, csr_src, dinv, bs + HIDDEN, x2b);

    // layer 2 (algebraic trick): x3 = dinv*(Σ x2') ; pool ; tiny GEMMs in k_final
    k_aggregate<false, false, false, false><<<NB_ROW, 256, 0, stream>>>(x2b, offs, csr_src, dinv, nullptr, bufA);
    k_pool2<<<dim3(NUM_GRAPHS, POOL_CHUNKS), 256, 0, stream>>>(bufA, gstart, part);

    k_final<<<NUM_GRAPHS, HIDDEN, 0, stream>>>(part, gstart,
                                               Ws + 2 * HIDDEN * HIDDEN, bs + 2 * HIDDEN,
                                               linW, linb, out);
}

// Round 9
// 368.451 us; speedup vs baseline: 1.3051x; 1.1171x over previous
//
#include <hip/hip_runtime.h>
#include <math.h>

#define N_NODES    100000
#define N_EDGES    1600000
#define HIDDEN     128
#define NUM_GRAPHS 64

constexpr int POOL_CHUNKS = 16;

// ---- two-level LDS-staged CSR build ----
constexpr int BINSHIFT = 10;
constexpr int BINSZ    = 1 << BINSHIFT;                  // 1024 nodes per bin
constexpr int NBIN     = (N_NODES + BINSZ - 1) / BINSZ;  // 98
constexpr int CH_E     = 8192;                           // edges per chunk
constexpr int NCH      = (N_EDGES + CH_E - 1) / CH_E;    // 196
constexpr int CAP1     = 160;  // per (bin,chunk): mean 84, +8.3 sigma
constexpr int CAP2     = 18432; // per bin: mean 16384, +16 sigma

// bf16 helpers (RNE)
static __device__ __forceinline__ unsigned short f2bf(float f) {
    unsigned u = __float_as_uint(f);
    u += 0x7FFFu + ((u >> 16) & 1u);
    return (unsigned short)(u >> 16);
}
static __device__ __forceinline__ float b2f(unsigned short h) {
    return __uint_as_float(((unsigned)h) << 16);
}

// ---------------- graph boundaries (batch is sorted) ----------------

__global__ void k_gbounds(const int* __restrict__ batch, int* __restrict__ gstart) {
    int i = blockIdx.x * blockDim.x + threadIdx.x;
    if (i >= N_NODES) return;
    int b = batch[i];
    if (i == 0) {
        for (int g = 0; g <= b; ++g) gstart[g] = 0;
    } else {
        int bp = batch[i - 1];
        for (int g = bp + 1; g <= b; ++g) gstart[g] = i;
    }
    if (i == N_NODES - 1) {
        for (int g = b + 1; g <= NUM_GRAPHS; ++g) gstart[g] = N_NODES;
    }
}

// ---------------- CSR build pass 1: LDS-binned, full-line flush ----------------

__global__ __launch_bounds__(256) void k_p1(const int* __restrict__ src,
                                            const int* __restrict__ dst,
                                            unsigned* __restrict__ slab,
                                            int* __restrict__ gcnt) {
    __shared__ unsigned bl[NBIN * CAP1];   // 62.7 KB
    __shared__ int c1[NBIN];

    const int ch = blockIdx.x;
    const int t  = threadIdx.x;
    for (int i = t; i < NBIN; i += 256) c1[i] = 0;
    __syncthreads();

    const int e0 = ch * CH_E;
    const int e1 = (e0 + CH_E < N_EDGES) ? e0 + CH_E : N_EDGES;
    for (int e = e0 + t; e < e1; e += 256) {
        int d = dst[e];
        int s = src[e];
        int b = d >> BINSHIFT;
        int pos = atomicAdd(&c1[b], 1);
        if (pos < CAP1)
            bl[b * CAP1 + pos] = ((unsigned)s << BINSHIFT) | (unsigned)(d & (BINSZ - 1));
    }
    __syncthreads();

    // flush: wave w handles bins w, w+4, ... (coalesced within wave)
    const int wv = t >> 6, ln = t & 63;
    for (int b = wv; b < NBIN; b += 4) {
        int n = c1[b]; n = n < CAP1 ? n : CAP1;
        unsigned* sp = &slab[((size_t)b * NCH + ch) * CAP1];
        for (int i = ln; i < n; i += 64) sp[i] = bl[b * CAP1 + i];
        if (ln == 0) gcnt[b * NCH + ch] = n;
    }
}

// ---------------- bin base scan (tiny) ----------------

__global__ void k_binscan(const int* __restrict__ gcnt, int* __restrict__ binbase) {
    __shared__ int T[NBIN];
    int t = threadIdx.x;
    if (t < NBIN) {
        int s = 0;
        for (int c = 0; c < NCH; ++c) s += gcnt[t * NCH + c];
        T[t] = s;
    }
    __syncthreads();
    if (t == 0) {
        int run = 0;
        for (int b = 0; b < NBIN; ++b) { binbase[b] = run; run += T[b]; }
        binbase[NBIN] = run;
    }
}

// ---------------- CSR build pass 2: per-bin finalize, latency-parallel ----------------

__global__ __launch_bounds__(1024) void k_p2(const unsigned* __restrict__ slab,
                                             const int* __restrict__ gcnt,
                                             const int* __restrict__ binbase,
                                             int* __restrict__ csr_src,
                                             int* __restrict__ offs,
                                             float* __restrict__ dinv) {
    __shared__ unsigned eb[CAP2];          // 72 KB
    __shared__ int cnt2[BINSZ];
    __shared__ int off2[BINSZ];
    __shared__ int cur[BINSZ];
    __shared__ int choff[NCH + 1];
    __shared__ int csc[256];

    const int bin = blockIdx.x;
    const int t   = threadIdx.x;

    cnt2[t] = 0; cur[t] = 0;               // blockDim == BINSZ == 1024
    if (t < 256) csc[t] = (t < NCH) ? gcnt[bin * NCH + t] : 0;
    __syncthreads();

    for (int off = 1; off < 256; off <<= 1) {
        int add = 0;
        if (t < 256 && t >= off) add = csc[t - off];
        __syncthreads();
        if (t < 256) csc[t] += add;
        __syncthreads();
    }
    if (t < NCH) {
        int v = gcnt[bin * NCH + t];
        choff[t] = csc[t] - v;             // exclusive
        if (t == NCH - 1) choff[NCH] = csc[t];
    }
    __syncthreads();
    int total = choff[NCH]; total = total < CAP2 ? total : CAP2;

    const int wv = t >> 6, ln = t & 63;
    for (int c = wv; c < NCH; c += 16) {
        int o = choff[c];
        int n = choff[c + 1] - o;
        const unsigned* sp = &slab[((size_t)bin * NCH + c) * CAP1];
        for (int i = ln; i < n; i += 64) {
            int idx = o + i;
            if (idx < CAP2) {
                unsigned v = sp[i];
                eb[idx] = v;
                atomicAdd(&cnt2[v & (BINSZ - 1)], 1);
            }
        }
    }
    __syncthreads();

    int mycnt = cnt2[t];
    off2[t] = mycnt;
    __syncthreads();
    for (int off = 1; off < BINSZ; off <<= 1) {
        int add = (t >= off) ? off2[t - off] : 0;
        __syncthreads();
        off2[t] += add;
        __syncthreads();
    }
    int excl = off2[t] - mycnt;
    __syncthreads();
    off2[t] = excl;
    __syncthreads();

    const int base  = binbase[bin];
    const int node0 = bin << BINSHIFT;
    int node = node0 + t;
    if (node < N_NODES) {
        offs[node] = base + excl;
        dinv[node] = rsqrtf((float)(mycnt + 1));   // +1 self-loop
    }
    if (bin == NBIN - 1 && t == 0) offs[N_NODES] = base + total;
    __syncthreads();

    for (int i = t; i < total; i += 1024) {
        unsigned v = eb[i];
        int lo = v & (BINSZ - 1);
        int p = atomicAdd(&cur[lo], 1);
        csr_src[base + off2[lo] + p] = (int)(v >> BINSHIFT);
    }
}

// ---------------- dense GEMM: Hb = dinv ⊙ (X @ W) in bf16 ----------------
// 128x128 tile, K-tiled (KT=32) double-buffered LDS: 68 KB -> 2 blocks/CU.
// 512 threads (8 waves), 4x8 micro-tile/thread. Prefetch next K-tile into
// registers during compute, ds_write after, 1 barrier per tile.

__global__ __launch_bounds__(512) void k_gemm(const float* __restrict__ X,
                                              const float* __restrict__ W,
                                              const float* __restrict__ dinv,
                                              unsigned short* __restrict__ Hb) {
    __shared__ float Xs[2][128][36];   // [buf][row][k] pitch 36 (144B, 16B-aligned)
    __shared__ float Wt[2][32][128];   // [buf][k][col]

    const int t    = threadIdx.x;
    const int row0 = blockIdx.x * 128;

    // stage tile 0 (k 0..31)
    #pragma unroll
    for (int i = 0; i < 2; ++i) {
        int idx = t + i * 512;
        int r  = idx >> 3, fc = idx & 7;
        int rg = row0 + r; rg = rg < N_NODES ? rg : N_NODES - 1;
        *(float4*)&Xs[0][r][fc * 4] = *(const float4*)&X[(size_t)rg * HIDDEN + fc * 4];
        int kr = idx >> 5, wc = idx & 31;
        *(float4*)&Wt[0][kr][wc * 4] = *(const float4*)&W[kr * HIDDEN + wc * 4];
    }
    __syncthreads();

    const int trow = t >> 4;   // 0..31 -> rows trow*4..+3
    const int tcol = t & 15;   // 0..15 -> cols tcol*4..+3, 64+tcol*4..+3

    float4 aA[4], aB[4];
    #pragma unroll
    for (int r = 0; r < 4; ++r) {
        aA[r] = make_float4(0.f, 0.f, 0.f, 0.f);
        aB[r] = make_float4(0.f, 0.f, 0.f, 0.f);
    }

    int cur = 0;
    #pragma unroll
    for (int kt = 0; kt < 4; ++kt) {
        // prefetch next K-tile into registers (overlaps with compute below)
        float4 px0, px1, pw0, pw1;
        if (kt < 3) {
            const int k0 = (kt + 1) * 32;
            {
                int idx = t;       int r = idx >> 3, fc = idx & 7;
                int rg = row0 + r; rg = rg < N_NODES ? rg : N_NODES - 1;
                px0 = *(const float4*)&X[(size_t)rg * HIDDEN + k0 + fc * 4];
            }
            {
                int idx = t + 512; int r = idx >> 3, fc = idx & 7;
                int rg = row0 + r; rg = rg < N_NODES ? rg : N_NODES - 1;
                px1 = *(const float4*)&X[(size_t)rg * HIDDEN + k0 + fc * 4];
            }
            {
                int idx = t;       int kr = idx >> 5, wc = idx & 31;
                pw0 = *(const float4*)&W[(k0 + kr) * HIDDEN + wc * 4];
            }
            {
                int idx = t + 512; int kr = idx >> 5, wc = idx & 31;
                pw1 = *(const float4*)&W[(k0 + kr) * HIDDEN + wc * 4];
            }
        }

        #pragma unroll 4
        for (int kk = 0; kk < 32; ++kk) {
            float4 wa = *(const float4*)&Wt[cur][kk][tcol * 4];
            float4 wb = *(const float4*)&Wt[cur][kk][64 + tcol * 4];
            float xs[4];
            #pragma unroll
            for (int r = 0; r < 4; ++r) xs[r] = Xs[cur][trow * 4 + r][kk];
            #pragma unroll
            for (int r = 0; r < 4; ++r) {
                aA[r].x += xs[r] * wa.x; aA[r].y += xs[r] * wa.y;
                aA[r].z += xs[r] * wa.z; aA[r].w += xs[r] * wa.w;
                aB[r].x += xs[r] * wb.x; aB[r].y += xs[r] * wb.y;
                aB[r].z += xs[r] * wb.z; aB[r].w += xs[r] * wb.w;
            }
        }

        if (kt < 3) {
            int nb = cur ^ 1;
            { int idx = t;       int r = idx >> 3, fc = idx & 7;  *(float4*)&Xs[nb][r][fc * 4] = px0; }
            { int idx = t + 512; int r = idx >> 3, fc = idx & 7;  *(float4*)&Xs[nb][r][fc * 4] = px1; }
            { int idx = t;       int kr = idx >> 5, wc = idx & 31; *(float4*)&Wt[nb][kr][wc * 4] = pw0; }
            { int idx = t + 512; int kr = idx >> 5, wc = idx & 31; *(float4*)&Wt[nb][kr][wc * 4] = pw1; }
            cur = nb;
        }
        __syncthreads();
    }

    #pragma unroll
    for (int r = 0; r < 4; ++r) {
        int row = row0 + trow * 4 + r;
        if (row < N_NODES) {
            float di = dinv[row];
            ushort4 oa, ob;
            oa.x = f2bf(aA[r].x * di); oa.y = f2bf(aA[r].y * di);
            oa.z = f2bf(aA[r].z * di); oa.w = f2bf(aA[r].w * di);
            ob.x = f2bf(aB[r].x * di); ob.y = f2bf(aB[r].y * di);
            ob.z = f2bf(aB[r].z * di); ob.w = f2bf(aB[r].w * di);
            *(ushort4*)&Hb[(size_t)row * HIDDEN + tcol * 4]      = oa;
            *(ushort4*)&Hb[(size_t)row * HIDDEN + 64 + tcol * 4] = ob;
        }
    }
}

// ---------------- fused aggregation over pre-scaled bf16 rows ----------------

template <bool OUT_BF16, bool BIAS, bool RELU, bool OUTSCALE>
__global__ __launch_bounds__(256) void k_aggregate(const unsigned short* __restrict__ Hb,
                                                   const int* __restrict__ offs,
                                                   const int* __restrict__ csr_src,
                                                   const float* __restrict__ dinv,
                                                   const float* __restrict__ bias,
                                                   void* __restrict__ outv) {
    int g    = threadIdx.x >> 5;       // node-in-block 0..7
    int lane = threadIdx.x & 31;
    int node = blockIdx.x * 8 + g;
    if (node >= N_NODES) return;
    int c4 = lane * 4;

    float di = dinv[node];
    ushort4 sv = *(const ushort4*)&Hb[(size_t)node * HIDDEN + c4];
    float4 acc;
    acc.x = b2f(sv.x); acc.y = b2f(sv.y); acc.z = b2f(sv.z); acc.w = b2f(sv.w);

    int j0 = offs[node], j1 = offs[node + 1];
    #pragma unroll 4
    for (int j = j0; j < j1; ++j) {
        int s = csr_src[j];
        ushort4 v = *(const ushort4*)&Hb[(size_t)s * HIDDEN + c4];
        acc.x += b2f(v.x); acc.y += b2f(v.y);
        acc.z += b2f(v.z); acc.w += b2f(v.w);
    }

    acc.x *= di; acc.y *= di; acc.z *= di; acc.w *= di;
    if (BIAS) {
        float4 bv = *(const float4*)&bias[c4];
        acc.x += bv.x; acc.y += bv.y; acc.z += bv.z; acc.w += bv.w;
    }
    if (RELU) {
        acc.x = fmaxf(acc.x, 0.f); acc.y = fmaxf(acc.y, 0.f);
        acc.z = fmaxf(acc.z, 0.f); acc.w = fmaxf(acc.w, 0.f);
    }
    if (OUTSCALE) {
        acc.x *= di; acc.y *= di; acc.z *= di; acc.w *= di;
    }
    if (OUT_BF16) {
        ushort4 o;
        o.x = f2bf(acc.x); o.y = f2bf(acc.y); o.z = f2bf(acc.z); o.w = f2bf(acc.w);
        *(ushort4*)&((unsigned short*)outv)[(size_t)node * HIDDEN + c4] = o;
    } else {
        *(float4*)&((float*)outv)[(size_t)node * HIDDEN + c4] = acc;
    }
}

// ---------------- pooling: segmented reduction, no atomics ----------------

__global__ __launch_bounds__(256) void k_pool2(const float* __restrict__ X,
                                               const int* __restrict__ gstart,
                                               float* __restrict__ part) {
    int g  = blockIdx.x;
    int ch = blockIdx.y;
    int start = gstart[g], end = gstart[g + 1];
    int len = end - start;
    int r0 = start + (int)((long long)len * ch / POOL_CHUNKS);
    int r1 = start + (int)((long long)len * (ch + 1) / POOL_CHUNKS);

    int rp = threadIdx.x >> 5;         // 0..7 rows in parallel
    int c4 = (threadIdx.x & 31) * 4;

    float4 acc = make_float4(0.f, 0.f, 0.f, 0.f);
    for (int r = r0 + rp; r < r1; r += 8) {
        float4 v = *(const float4*)&X[(size_t)r * HIDDEN + c4];
        acc.x += v.x; acc.y += v.y; acc.z += v.z; acc.w += v.w;
    }

    __shared__ float4 sh[256];
    sh[threadIdx.x] = acc;
    __syncthreads();
    #pragma unroll
    for (int off = 4; off >= 1; off >>= 1) {
        if (rp < off) {
            float4 o = sh[(rp + off) * 32 + (threadIdx.x & 31)];
            float4 m = sh[threadIdx.x];
            m.x += o.x; m.y += o.y; m.z += o.z; m.w += o.w;
            sh[threadIdx.x] = m;
        }
        __syncthreads();
    }
    if (rp == 0) {
        float4 v = sh[threadIdx.x];
        *(float4*)&part[((size_t)g * POOL_CHUNKS + ch) * HIDDEN + c4] = v;
    }
}

// ---------------- final: out = ((Σpart/cnt) @ W2 + b2) @ linW + linb ----------------

__global__ void k_final(const float* __restrict__ part, const int* __restrict__ gstart,
                        const float* __restrict__ W2, const float* __restrict__ b2,
                        const float* __restrict__ linW, const float* __restrict__ linb,
                        float* __restrict__ out) {
    __shared__ float m[HIDDEN];
    __shared__ float t[HIDDEN];
    int g = blockIdx.x;
    int c = threadIdx.x;
    float s = 0.f;
    #pragma unroll
    for (int ch = 0; ch < POOL_CHUNKS; ++ch)
        s += part[((size_t)g * POOL_CHUNKS + ch) * HIDDEN + c];
    float cnt = fmaxf((float)(gstart[g + 1] - gstart[g]), 1.0f);
    m[c] = s / cnt;
    __syncthreads();
    float acc = b2[c];
    #pragma unroll 4
    for (int k = 0; k < HIDDEN; ++k) acc += m[k] * W2[k * HIDDEN + c];
    t[c] = acc;
    __syncthreads();
    if (c < 16) {
        float o = linb[c];
        #pragma unroll 4
        for (int k = 0; k < HIDDEN; ++k) o += t[k] * linW[k * 16 + c];
        out[g * 16 + c] = o;
    }
}

// ---------------- launch ----------------

extern "C" void kernel_launch(void* const* d_in, const int* in_sizes, int n_in,
                              void* d_out, int out_size, void* d_ws, size_t ws_size,
                              hipStream_t stream) {
    const float* x     = (const float*)d_in[0];
    const int*   edge  = (const int*)d_in[1];   // [2, E] flat
    const int*   batch = (const int*)d_in[2];
    const float* Ws    = (const float*)d_in[3]; // [3,128,128]
    const float* bs    = (const float*)d_in[4]; // [3,128]
    const float* linW  = (const float*)d_in[5]; // [128,16]
    const float* linb  = (const float*)d_in[6]; // [16]
    float* out = (float*)d_out;

    const int* src = edge;
    const int* dst = edge + N_EDGES;

    // workspace layout
    float* bufA = (float*)d_ws;                       // N*128 fp32 (x1, then x3)
    unsigned* slab = (unsigned*)bufA;                 // NBIN*NCH*CAP1 u32 (12.3MB) — CSR-build
                                                      // scratch; dead before agg1 writes bufA
    float* bufBreg = bufA + (size_t)N_NODES * HIDDEN; // N*128 fp32-sized region, carved:
    unsigned short* hb  = (unsigned short*)bufBreg;                            // N*128 bf16
    unsigned short* x2b = (unsigned short*)bufBreg + (size_t)N_NODES * HIDDEN; // N*128 bf16
    float* dinv = bufBreg + (size_t)N_NODES * HIDDEN; // N
    float* part = dinv + N_NODES;                     // 64*16*128
    int* offs    = (int*)(part + NUM_GRAPHS * POOL_CHUNKS * HIDDEN); // N+1
    int* csr_src = offs + N_NODES + 1;                // E
    int* gstart  = csr_src + N_EDGES;                 // NUM_GRAPHS+1
    int* gcnt    = gstart + NUM_GRAPHS + 1;           // NBIN*NCH
    int* binbase = gcnt + NBIN * NCH;                 // NBIN+1

    const int NB_N    = (N_NODES + 255) / 256;   // 391
    const int NB_ROW  = N_NODES / 8;             // 12500
    const int NB_GEMM = (N_NODES + 127) / 128;   // 782

    // CSR build (also produces offs, dinv) — LDS-staged, no global atomics
    k_p1<<<NCH, 256, 0, stream>>>(src, dst, slab, gcnt);
    k_binscan<<<1, 128, 0, stream>>>(gcnt, binbase);
    k_p2<<<NBIN, 1024, 0, stream>>>(slab, gcnt, binbase, csr_src, offs, dinv);
    k_gbounds<<<NB_N, 256, 0, stream>>>(batch, gstart);

    // layer 0: hb = dinv ⊙ (x@W0) ; x1 = relu(dinv*(Σ hb) + b0)         [fp32 out]
    k_gemm<<<NB_GEMM, 512, 0, stream>>>(x, Ws, dinv, hb);
    k_aggregate<false, true, true, false><<<NB_ROW, 256, 0, stream>>>(hb, offs, csr_src, dinv, bs, bufA);

    // layer 1: hb = dinv ⊙ (x1@W1) ; x2' = dinv*relu(dinv*(Σ hb) + b1)  [bf16 out, pre-scaled]
    k_gemm<<<NB_GEMM, 512, 0, stream>>>(bufA, Ws + HIDDEN * HIDDEN, dinv, hb);
    k_aggregate<true, true, true, true><<<NB_ROW, 256, 0, stream>>>(hb, offs, csr_src, dinv, bs + HIDDEN, x2b);

    // layer 2 (algebraic trick): x3 = dinv*(Σ x2') ; pool ; tiny GEMMs in k_final
    k_aggregate<false, false, false, false><<<NB_ROW, 256, 0, stream>>>(x2b, offs, csr_src, dinv, nullptr, bufA);
    k_pool2<<<dim3(NUM_GRAPHS, POOL_CHUNKS), 256, 0, stream>>>(bufA, gstart, part);

    k_final<<<NUM_GRAPHS, HIDDEN, 0, stream>>>(part, gstart,
                                               Ws + 2 * HIDDEN * HIDDEN, bs + 2 * HIDDEN,
                                               linW, linb, out);
}

// Round 10
// 309.321 us; speedup vs baseline: 1.5546x; 1.1912x over previous
//
#include <hip/hip_runtime.h>
#include <math.h>

#define N_NODES    100000
#define N_EDGES    1600000
#define HIDDEN     128
#define NUM_GRAPHS 64

constexpr int POOL_CHUNKS = 16;

// ---- two-level LDS-staged CSR build ----
constexpr int BINSHIFT = 10;
constexpr int BINSZ    = 1 << BINSHIFT;                  // 1024 nodes per bin
constexpr int NBIN     = (N_NODES + BINSZ - 1) / BINSZ;  // 98
constexpr int CH_E     = 8192;                           // edges per chunk
constexpr int NCH      = (N_EDGES + CH_E - 1) / CH_E;    // 196
constexpr int CAP1     = 160;  // per (bin,chunk): mean 84, +8.3 sigma
constexpr int CAP2     = 18432; // per bin: mean 16384, +16 sigma

// bf16 helper (kept for reference paths)
static __device__ __forceinline__ float b2f(unsigned short h) {
    return __uint_as_float(((unsigned)h) << 16);
}

// ---------------- fp8 e4m3fn helpers (OCP, native on gfx950) ----------------

typedef float floatx2 __attribute__((ext_vector_type(2)));

#if __has_builtin(__builtin_amdgcn_cvt_pk_f32_fp8) && __has_builtin(__builtin_amdgcn_cvt_pk_fp8_f32)
#define FP8_HW 1
#else
#define FP8_HW 0
#endif

static __device__ __forceinline__ float4 dec4_e4m3(unsigned u) {
#if FP8_HW
    floatx2 lo = __builtin_amdgcn_cvt_pk_f32_fp8((int)u, false);
    floatx2 hi = __builtin_amdgcn_cvt_pk_f32_fp8((int)u, true);
    return make_float4(lo[0], lo[1], hi[0], hi[1]);
#else
    float t[4];
    #pragma unroll
    for (int i = 0; i < 4; ++i) {
        unsigned x = (u >> (8 * i)) & 0xFFu;
        unsigned s = x >> 7, e = (x >> 3) & 15u, m = x & 7u;
        float fn = __uint_as_float((s << 31) | ((e + 120u) << 23) | (m << 20));
        float fs = (float)m * 0.001953125f;          // m * 2^-9
        if (s) fs = -fs;
        t[i] = e ? fn : fs;
    }
    return make_float4(t[0], t[1], t[2], t[3]);
#endif
}

static __device__ __forceinline__ unsigned char enc1_e4m3(float v) {
    unsigned u = __float_as_uint(v);
    unsigned s = u >> 31;
    float a = fabsf(v);
    if (a >= 448.f) return (unsigned char)((s << 7) | 0x7Eu);       // saturate to 448
    if (a < 0.015625f) {                                            // subnormal: m * 2^-9
        unsigned q = (unsigned)rintf(a * 512.f);
        return (unsigned char)((s << 7) | q);                       // q==8 -> 0x08 == 2^-6, correct
    }
    unsigned au = u & 0x7FFFFFFFu;
    au += 0x7FFFFu + ((au >> 20) & 1u);                             // RNE at 3-bit mantissa
    unsigned e = (au >> 23) - 120u;
    unsigned m = (au >> 20) & 7u;
    if (e >= 15u && m >= 7u) { e = 15u; m = 6u; }
    return (unsigned char)((s << 7) | (e << 3) | m);
}

static __device__ __forceinline__ unsigned enc4_e4m3(float a, float b, float c, float d) {
#if FP8_HW
    int v = 0;
    v = __builtin_amdgcn_cvt_pk_fp8_f32(a, b, v, false);
    v = __builtin_amdgcn_cvt_pk_fp8_f32(c, d, v, true);
    return (unsigned)v;
#else
    return (unsigned)enc1_e4m3(a) | ((unsigned)enc1_e4m3(b) << 8) |
           ((unsigned)enc1_e4m3(c) << 16) | ((unsigned)enc1_e4m3(d) << 24);
#endif
}

// ---------------- graph boundaries (batch is sorted) ----------------

__global__ void k_gbounds(const int* __restrict__ batch, int* __restrict__ gstart) {
    int i = blockIdx.x * blockDim.x + threadIdx.x;
    if (i >= N_NODES) return;
    int b = batch[i];
    if (i == 0) {
        for (int g = 0; g <= b; ++g) gstart[g] = 0;
    } else {
        int bp = batch[i - 1];
        for (int g = bp + 1; g <= b; ++g) gstart[g] = i;
    }
    if (i == N_NODES - 1) {
        for (int g = b + 1; g <= NUM_GRAPHS; ++g) gstart[g] = N_NODES;
    }
}

// ---------------- CSR build pass 1: LDS-binned, full-line flush ----------------

__global__ __launch_bounds__(256) void k_p1(const int* __restrict__ src,
                                            const int* __restrict__ dst,
                                            unsigned* __restrict__ slab,
                                            int* __restrict__ gcnt) {
    __shared__ unsigned bl[NBIN * CAP1];   // 62.7 KB
    __shared__ int c1[NBIN];

    const int ch = blockIdx.x;
    const int t  = threadIdx.x;
    for (int i = t; i < NBIN; i += 256) c1[i] = 0;
    __syncthreads();

    const int e0 = ch * CH_E;
    const int e1 = (e0 + CH_E < N_EDGES) ? e0 + CH_E : N_EDGES;
    for (int e = e0 + t; e < e1; e += 256) {
        int d = dst[e];
        int s = src[e];
        int b = d >> BINSHIFT;
        int pos = atomicAdd(&c1[b], 1);
        if (pos < CAP1)
            bl[b * CAP1 + pos] = ((unsigned)s << BINSHIFT) | (unsigned)(d & (BINSZ - 1));
    }
    __syncthreads();

    const int wv = t >> 6, ln = t & 63;
    for (int b = wv; b < NBIN; b += 4) {
        int n = c1[b]; n = n < CAP1 ? n : CAP1;
        unsigned* sp = &slab[((size_t)b * NCH + ch) * CAP1];
        for (int i = ln; i < n; i += 64) sp[i] = bl[b * CAP1 + i];
        if (ln == 0) gcnt[b * NCH + ch] = n;
    }
}

// ---------------- bin base scan (tiny) ----------------

__global__ void k_binscan(const int* __restrict__ gcnt, int* __restrict__ binbase) {
    __shared__ int T[NBIN];
    int t = threadIdx.x;
    if (t < NBIN) {
        int s = 0;
        for (int c = 0; c < NCH; ++c) s += gcnt[t * NCH + c];
        T[t] = s;
    }
    __syncthreads();
    if (t == 0) {
        int run = 0;
        for (int b = 0; b < NBIN; ++b) { binbase[b] = run; run += T[b]; }
        binbase[NBIN] = run;
    }
}

// ---------------- CSR build pass 2: per-bin finalize, latency-parallel ----------------

__global__ __launch_bounds__(1024) void k_p2(const unsigned* __restrict__ slab,
                                             const int* __restrict__ gcnt,
                                             const int* __restrict__ binbase,
                                             int* __restrict__ csr_src,
                                             int* __restrict__ offs,
                                             float* __restrict__ dinv) {
    __shared__ unsigned eb[CAP2];          // 72 KB
    __shared__ int cnt2[BINSZ];
    __shared__ int off2[BINSZ];
    __shared__ int cur[BINSZ];
    __shared__ int choff[NCH + 1];
    __shared__ int csc[256];

    const int bin = blockIdx.x;
    const int t   = threadIdx.x;

    cnt2[t] = 0; cur[t] = 0;               // blockDim == BINSZ == 1024
    if (t < 256) csc[t] = (t < NCH) ? gcnt[bin * NCH + t] : 0;
    __syncthreads();

    for (int off = 1; off < 256; off <<= 1) {
        int add = 0;
        if (t < 256 && t >= off) add = csc[t - off];
        __syncthreads();
        if (t < 256) csc[t] += add;
        __syncthreads();
    }
    if (t < NCH) {
        int v = gcnt[bin * NCH + t];
        choff[t] = csc[t] - v;             // exclusive
        if (t == NCH - 1) choff[NCH] = csc[t];
    }
    __syncthreads();
    int total = choff[NCH]; total = total < CAP2 ? total : CAP2;

    const int wv = t >> 6, ln = t & 63;
    for (int c = wv; c < NCH; c += 16) {
        int o = choff[c];
        int n = choff[c + 1] - o;
        const unsigned* sp = &slab[((size_t)bin * NCH + c) * CAP1];
        for (int i = ln; i < n; i += 64) {
            int idx = o + i;
            if (idx < CAP2) {
                unsigned v = sp[i];
                eb[idx] = v;
                atomicAdd(&cnt2[v & (BINSZ - 1)], 1);
            }
        }
    }
    __syncthreads();

    int mycnt = cnt2[t];
    off2[t] = mycnt;
    __syncthreads();
    for (int off = 1; off < BINSZ; off <<= 1) {
        int add = (t >= off) ? off2[t - off] : 0;
        __syncthreads();
        off2[t] += add;
        __syncthreads();
    }
    int excl = off2[t] - mycnt;
    __syncthreads();
    off2[t] = excl;
    __syncthreads();

    const int base  = binbase[bin];
    const int node0 = bin << BINSHIFT;
    int node = node0 + t;
    if (node < N_NODES) {
        offs[node] = base + excl;
        dinv[node] = rsqrtf((float)(mycnt + 1));   // +1 self-loop
    }
    if (bin == NBIN - 1 && t == 0) offs[N_NODES] = base + total;
    __syncthreads();

    for (int i = t; i < total; i += 1024) {
        unsigned v = eb[i];
        int lo = v & (BINSZ - 1);
        int p = atomicAdd(&cur[lo], 1);
        csr_src[base + off2[lo] + p] = (int)(v >> BINSHIFT);
    }
}

// ---------------- dense GEMM: Hb8 = fp8(8 * dinv ⊙ (X @ W)) ----------------
// 128x128 tile, K-tiled (KT=32) double-buffered LDS, 512 threads, 4x8 micro-tile.

__global__ __launch_bounds__(512) void k_gemm(const float* __restrict__ X,
                                              const float* __restrict__ W,
                                              const float* __restrict__ dinv,
                                              unsigned char* __restrict__ Hb8) {
    __shared__ float Xs[2][128][36];   // [buf][row][k]
    __shared__ float Wt[2][32][128];   // [buf][k][col]

    const int t    = threadIdx.x;
    const int row0 = blockIdx.x * 128;

    #pragma unroll
    for (int i = 0; i < 2; ++i) {
        int idx = t + i * 512;
        int r  = idx >> 3, fc = idx & 7;
        int rg = row0 + r; rg = rg < N_NODES ? rg : N_NODES - 1;
        *(float4*)&Xs[0][r][fc * 4] = *(const float4*)&X[(size_t)rg * HIDDEN + fc * 4];
        int kr = idx >> 5, wc = idx & 31;
        *(float4*)&Wt[0][kr][wc * 4] = *(const float4*)&W[kr * HIDDEN + wc * 4];
    }
    __syncthreads();

    const int trow = t >> 4;   // 0..31
    const int tcol = t & 15;   // 0..15

    float4 aA[4], aB[4];
    #pragma unroll
    for (int r = 0; r < 4; ++r) {
        aA[r] = make_float4(0.f, 0.f, 0.f, 0.f);
        aB[r] = make_float4(0.f, 0.f, 0.f, 0.f);
    }

    int cur = 0;
    #pragma unroll
    for (int kt = 0; kt < 4; ++kt) {
        float4 px0, px1, pw0, pw1;
        if (kt < 3) {
            const int k0 = (kt + 1) * 32;
            {
                int idx = t;       int r = idx >> 3, fc = idx & 7;
                int rg = row0 + r; rg = rg < N_NODES ? rg : N_NODES - 1;
                px0 = *(const float4*)&X[(size_t)rg * HIDDEN + k0 + fc * 4];
            }
            {
                int idx = t + 512; int r = idx >> 3, fc = idx & 7;
                int rg = row0 + r; rg = rg < N_NODES ? rg : N_NODES - 1;
                px1 = *(const float4*)&X[(size_t)rg * HIDDEN + k0 + fc * 4];
            }
            {
                int idx = t;       int kr = idx >> 5, wc = idx & 31;
                pw0 = *(const float4*)&W[(k0 + kr) * HIDDEN + wc * 4];
            }
            {
                int idx = t + 512; int kr = idx >> 5, wc = idx & 31;
                pw1 = *(const float4*)&W[(k0 + kr) * HIDDEN + wc * 4];
            }
        }

        #pragma unroll 4
        for (int kk = 0; kk < 32; ++kk) {
            float4 wa = *(const float4*)&Wt[cur][kk][tcol * 4];
            float4 wb = *(const float4*)&Wt[cur][kk][64 + tcol * 4];
            float xs[4];
            #pragma unroll
            for (int r = 0; r < 4; ++r) xs[r] = Xs[cur][trow * 4 + r][kk];
            #pragma unroll
            for (int r = 0; r < 4; ++r) {
                aA[r].x += xs[r] * wa.x; aA[r].y += xs[r] * wa.y;
                aA[r].z += xs[r] * wa.z; aA[r].w += xs[r] * wa.w;
                aB[r].x += xs[r] * wb.x; aB[r].y += xs[r] * wb.y;
                aB[r].z += xs[r] * wb.z; aB[r].w += xs[r] * wb.w;
            }
        }

        if (kt < 3) {
            int nb = cur ^ 1;
            { int idx = t;       int r = idx >> 3, fc = idx & 7;  *(float4*)&Xs[nb][r][fc * 4] = px0; }
            { int idx = t + 512; int r = idx >> 3, fc = idx & 7;  *(float4*)&Xs[nb][r][fc * 4] = px1; }
            { int idx = t;       int kr = idx >> 5, wc = idx & 31; *(float4*)&Wt[nb][kr][wc * 4] = pw0; }
            { int idx = t + 512; int kr = idx >> 5, wc = idx & 31; *(float4*)&Wt[nb][kr][wc * 4] = pw1; }
            cur = nb;
        }
        __syncthreads();
    }

    #pragma unroll
    for (int r = 0; r < 4; ++r) {
        int row = row0 + trow * 4 + r;
        if (row < N_NODES) {
            float d8 = dinv[row] * 8.f;          // encode pre-scale
            unsigned pa = enc4_e4m3(aA[r].x * d8, aA[r].y * d8, aA[r].z * d8, aA[r].w * d8);
            unsigned pb = enc4_e4m3(aB[r].x * d8, aB[r].y * d8, aB[r].z * d8, aB[r].w * d8);
            *(unsigned*)&Hb8[(size_t)row * HIDDEN + tcol * 4]      = pa;
            *(unsigned*)&Hb8[(size_t)row * HIDDEN + 64 + tcol * 4] = pb;
        }
    }
}

// ---------------- fused aggregation over pre-scaled fp8 rows ----------------
// in: rows pre-scaled by dinv[src] (and encode scale 1/in_dec).
// out f32: post(di*in_dec*acc [+bias][relu]); out fp8: enc(di*out_enc*post(...)).

template <bool OUT_FP8, bool BIAS, bool RELU>
__global__ __launch_bounds__(256) void k_aggregate(const unsigned char* __restrict__ Hb8,
                                                   const int* __restrict__ offs,
                                                   const int* __restrict__ csr_src,
                                                   const float* __restrict__ dinv,
                                                   const float* __restrict__ bias,
                                                   void* __restrict__ outv,
                                                   float in_dec, float out_enc) {
    int g    = threadIdx.x >> 5;       // node-in-block 0..7
    int lane = threadIdx.x & 31;
    int node = blockIdx.x * 8 + g;
    if (node >= N_NODES) return;
    int c4 = lane * 4;

    float di = dinv[node];
    float4 acc = dec4_e4m3(*(const unsigned*)&Hb8[(size_t)node * HIDDEN + c4]);

    int j0 = offs[node], j1 = offs[node + 1];
    #pragma unroll 4
    for (int j = j0; j < j1; ++j) {
        int s = csr_src[j];
        float4 v = dec4_e4m3(*(const unsigned*)&Hb8[(size_t)s * HIDDEN + c4]);
        acc.x += v.x; acc.y += v.y; acc.z += v.z; acc.w += v.w;
    }

    float ms = di * in_dec;
    acc.x *= ms; acc.y *= ms; acc.z *= ms; acc.w *= ms;
    if (BIAS) {
        float4 bv = *(const float4*)&bias[c4];
        acc.x += bv.x; acc.y += bv.y; acc.z += bv.z; acc.w += bv.w;
    }
    if (RELU) {
        acc.x = fmaxf(acc.x, 0.f); acc.y = fmaxf(acc.y, 0.f);
        acc.z = fmaxf(acc.z, 0.f); acc.w = fmaxf(acc.w, 0.f);
    }
    if (OUT_FP8) {
        float es = di * out_enc;
        unsigned p = enc4_e4m3(acc.x * es, acc.y * es, acc.z * es, acc.w * es);
        *(unsigned*)&((unsigned char*)outv)[(size_t)node * HIDDEN + c4] = p;
    } else {
        *(float4*)&((float*)outv)[(size_t)node * HIDDEN + c4] = acc;
    }
}

// ---------------- pooling: segmented reduction, no atomics ----------------

__global__ __launch_bounds__(256) void k_pool2(const float* __restrict__ X,
                                               const int* __restrict__ gstart,
                                               float* __restrict__ part) {
    int g  = blockIdx.x;
    int ch = blockIdx.y;
    int start = gstart[g], end = gstart[g + 1];
    int len = end - start;
    int r0 = start + (int)((long long)len * ch / POOL_CHUNKS);
    int r1 = start + (int)((long long)len * (ch + 1) / POOL_CHUNKS);

    int rp = threadIdx.x >> 5;         // 0..7 rows in parallel
    int c4 = (threadIdx.x & 31) * 4;

    float4 acc = make_float4(0.f, 0.f, 0.f, 0.f);
    for (int r = r0 + rp; r < r1; r += 8) {
        float4 v = *(const float4*)&X[(size_t)r * HIDDEN + c4];
        acc.x += v.x; acc.y += v.y; acc.z += v.z; acc.w += v.w;
    }

    __shared__ float4 sh[256];
    sh[threadIdx.x] = acc;
    __syncthreads();
    #pragma unroll
    for (int off = 4; off >= 1; off >>= 1) {
        if (rp < off) {
            float4 o = sh[(rp + off) * 32 + (threadIdx.x & 31)];
            float4 m = sh[threadIdx.x];
            m.x += o.x; m.y += o.y; m.z += o.z; m.w += o.w;
            sh[threadIdx.x] = m;
        }
        __syncthreads();
    }
    if (rp == 0) {
        float4 v = sh[threadIdx.x];
        *(float4*)&part[((size_t)g * POOL_CHUNKS + ch) * HIDDEN + c4] = v;
    }
}

// ---------------- final: out = ((Σpart/cnt) @ W2 + b2) @ linW + linb ----------------

__global__ void k_final(const float* __restrict__ part, const int* __restrict__ gstart,
                        const float* __restrict__ W2, const float* __restrict__ b2,
                        const float* __restrict__ linW, const float* __restrict__ linb,
                        float* __restrict__ out) {
    __shared__ float m[HIDDEN];
    __shared__ float t[HIDDEN];
    int g = blockIdx.x;
    int c = threadIdx.x;
    float s = 0.f;
    #pragma unroll
    for (int ch = 0; ch < POOL_CHUNKS; ++ch)
        s += part[((size_t)g * POOL_CHUNKS + ch) * HIDDEN + c];
    float cnt = fmaxf((float)(gstart[g + 1] - gstart[g]), 1.0f);
    m[c] = s / cnt;
    __syncthreads();
    float acc = b2[c];
    #pragma unroll 4
    for (int k = 0; k < HIDDEN; ++k) acc += m[k] * W2[k * HIDDEN + c];
    t[c] = acc;
    __syncthreads();
    if (c < 16) {
        float o = linb[c];
        #pragma unroll 4
        for (int k = 0; k < HIDDEN; ++k) o += t[k] * linW[k * 16 + c];
        out[g * 16 + c] = o;
    }
}

// ---------------- launch ----------------

extern "C" void kernel_launch(void* const* d_in, const int* in_sizes, int n_in,
                              void* d_out, int out_size, void* d_ws, size_t ws_size,
                              hipStream_t stream) {
    const float* x     = (const float*)d_in[0];
    const int*   edge  = (const int*)d_in[1];   // [2, E] flat
    const int*   batch = (const int*)d_in[2];
    const float* Ws    = (const float*)d_in[3]; // [3,128,128]
    const float* bs    = (const float*)d_in[4]; // [3,128]
    const float* linW  = (const float*)d_in[5]; // [128,16]
    const float* linb  = (const float*)d_in[6]; // [16]
    float* out = (float*)d_out;

    const int* src = edge;
    const int* dst = edge + N_EDGES;

    // workspace layout
    float* bufA = (float*)d_ws;                       // N*128 fp32 (x1, then x3)
    unsigned* slab = (unsigned*)bufA;                 // NBIN*NCH*CAP1 u32 (12.3MB) — CSR-build
                                                      // scratch; dead before agg1 writes bufA
    float* bufBreg = bufA + (size_t)N_NODES * HIDDEN; // N*128 fp32-sized region, carved:
    unsigned char* hb8  = (unsigned char*)bufBreg;                           // N*128 fp8
    unsigned char* x2b8 = (unsigned char*)bufBreg + (size_t)N_NODES * HIDDEN; // N*128 fp8
    float* dinv = bufBreg + (size_t)N_NODES * HIDDEN; // N
    float* part = dinv + N_NODES;                     // 64*16*128
    int* offs    = (int*)(part + NUM_GRAPHS * POOL_CHUNKS * HIDDEN); // N+1
    int* csr_src = offs + N_NODES + 1;                // E
    int* gstart  = csr_src + N_EDGES;                 // NUM_GRAPHS+1
    int* gcnt    = gstart + NUM_GRAPHS + 1;           // NBIN*NCH
    int* binbase = gcnt + NBIN * NCH;                 // NBIN+1

    const int NB_N    = (N_NODES + 255) / 256;   // 391
    const int NB_ROW  = N_NODES / 8;             // 12500
    const int NB_GEMM = (N_NODES + 127) / 128;   // 782

    // CSR build (also produces offs, dinv) — LDS-staged, no global atomics
    k_p1<<<NCH, 256, 0, stream>>>(src, dst, slab, gcnt);
    k_binscan<<<1, 128, 0, stream>>>(gcnt, binbase);
    k_p2<<<NBIN, 1024, 0, stream>>>(slab, gcnt, binbase, csr_src, offs, dinv);
    k_gbounds<<<NB_N, 256, 0, stream>>>(batch, gstart);

    // layer 0: hb8 = fp8(8*dinv*(x@W0)) ; x1 = relu(dinv*Σ/8 + b0)      [f32 out]
    k_gemm<<<NB_GEMM, 512, 0, stream>>>(x, Ws, dinv, hb8);
    k_aggregate<false, true, true><<<NB_ROW, 256, 0, stream>>>(hb8, offs, csr_src, dinv, bs, bufA, 0.125f, 1.f);

    // layer 1: hb8 = fp8(8*dinv*(x1@W1)) ; x2' = fp8(32*dinv*relu(dinv*Σ/8 + b1))
    k_gemm<<<NB_GEMM, 512, 0, stream>>>(bufA, Ws + HIDDEN * HIDDEN, dinv, hb8);
    k_aggregate<true, true, true><<<NB_ROW, 256, 0, stream>>>(hb8, offs, csr_src, dinv, bs + HIDDEN, x2b8, 0.125f, 32.f);

    // layer 2 (algebraic trick): x3 = dinv*Σ/32 ; pool ; tiny GEMMs in k_final
    k_aggregate<false, false, false><<<NB_ROW, 256, 0, stream>>>(x2b8, offs, csr_src, dinv, nullptr, bufA, 0.03125f, 1.f);
    k_pool2<<<dim3(NUM_GRAPHS, POOL_CHUNKS), 256, 0, stream>>>(bufA, gstart, part);

    k_final<<<NUM_GRAPHS, HIDDEN, 0, stream>>>(part, gstart,
                                               Ws + 2 * HIDDEN * HIDDEN, bs + 2 * HIDDEN,
                                               linW, linb, out);
}

// Round 11
// 247.898 us; speedup vs baseline: 1.9398x; 1.2478x over previous
//
#include <hip/hip_runtime.h>
#include <math.h>

#define N_NODES    100000
#define N_EDGES    1600000
#define HIDDEN     128
#define NUM_GRAPHS 64

constexpr int POOL_CHUNKS = 16;

// ---- two-level LDS-staged CSR build ----
constexpr int BINSHIFT = 10;
constexpr int BINSZ    = 1 << BINSHIFT;                  // 1024 nodes per bin
constexpr int NBIN     = (N_NODES + BINSZ - 1) / BINSZ;  // 98
constexpr int CH_E     = 8192;                           // edges per chunk
constexpr int NCH      = (N_EDGES + CH_E - 1) / CH_E;    // 196
constexpr int CAP1     = 160;  // per (bin,chunk): mean 84, +8.3 sigma
constexpr int CAP2     = 18432; // per bin: mean 16384, +16 sigma

// ---------------- bf16 helpers ----------------

static __device__ __forceinline__ unsigned short f2bf(float f) {
    unsigned u = __float_as_uint(f);
    u += 0x7FFFu + ((u >> 16) & 1u);
    return (unsigned short)(u >> 16);
}
static __device__ __forceinline__ float b2f(unsigned short h) {
    return __uint_as_float(((unsigned)h) << 16);
}

// ---------------- fp8 e4m3fn helpers (OCP, native on gfx950) ----------------

typedef float floatx2 __attribute__((ext_vector_type(2)));
typedef short bf16x8  __attribute__((ext_vector_type(8)));
typedef float f32x4v  __attribute__((ext_vector_type(4)));

#if __has_builtin(__builtin_amdgcn_cvt_pk_f32_fp8) && __has_builtin(__builtin_amdgcn_cvt_pk_fp8_f32)
#define FP8_HW 1
#else
#define FP8_HW 0
#endif

static __device__ __forceinline__ float4 dec4_e4m3(unsigned u) {
#if FP8_HW
    floatx2 lo = __builtin_amdgcn_cvt_pk_f32_fp8((int)u, false);
    floatx2 hi = __builtin_amdgcn_cvt_pk_f32_fp8((int)u, true);
    return make_float4(lo[0], lo[1], hi[0], hi[1]);
#else
    float t[4];
    #pragma unroll
    for (int i = 0; i < 4; ++i) {
        unsigned x = (u >> (8 * i)) & 0xFFu;
        unsigned s = x >> 7, e = (x >> 3) & 15u, m = x & 7u;
        float fn = __uint_as_float((s << 31) | ((e + 120u) << 23) | (m << 20));
        float fs = (float)m * 0.001953125f;
        if (s) fs = -fs;
        t[i] = e ? fn : fs;
    }
    return make_float4(t[0], t[1], t[2], t[3]);
#endif
}

static __device__ __forceinline__ unsigned char enc1_e4m3(float v) {
    unsigned u = __float_as_uint(v);
    unsigned s = u >> 31;
    float a = fabsf(v);
    if (a >= 448.f) return (unsigned char)((s << 7) | 0x7Eu);
    if (a < 0.015625f) {
        unsigned q = (unsigned)rintf(a * 512.f);
        return (unsigned char)((s << 7) | q);
    }
    unsigned au = u & 0x7FFFFFFFu;
    au += 0x7FFFFu + ((au >> 20) & 1u);
    unsigned e = (au >> 23) - 120u;
    unsigned m = (au >> 20) & 7u;
    if (e >= 15u && m >= 7u) { e = 15u; m = 6u; }
    return (unsigned char)((s << 7) | (e << 3) | m);
}

static __device__ __forceinline__ unsigned enc4_e4m3(float a, float b, float c, float d) {
#if FP8_HW
    int v = 0;
    v = __builtin_amdgcn_cvt_pk_fp8_f32(a, b, v, false);
    v = __builtin_amdgcn_cvt_pk_fp8_f32(c, d, v, true);
    return (unsigned)v;
#else
    return (unsigned)enc1_e4m3(a) | ((unsigned)enc1_e4m3(b) << 8) |
           ((unsigned)enc1_e4m3(c) << 16) | ((unsigned)enc1_e4m3(d) << 24);
#endif
}

// ---------------- graph boundaries (batch is sorted) ----------------

__global__ void k_gbounds(const int* __restrict__ batch, int* __restrict__ gstart) {
    int i = blockIdx.x * blockDim.x + threadIdx.x;
    if (i >= N_NODES) return;
    int b = batch[i];
    if (i == 0) {
        for (int g = 0; g <= b; ++g) gstart[g] = 0;
    } else {
        int bp = batch[i - 1];
        for (int g = bp + 1; g <= b; ++g) gstart[g] = i;
    }
    if (i == N_NODES - 1) {
        for (int g = b + 1; g <= NUM_GRAPHS; ++g) gstart[g] = N_NODES;
    }
}

// ---------------- CSR build pass 1: LDS-binned, full-line flush ----------------

__global__ __launch_bounds__(256) void k_p1(const int* __restrict__ src,
                                            const int* __restrict__ dst,
                                            unsigned* __restrict__ slab,
                                            int* __restrict__ gcnt) {
    __shared__ unsigned bl[NBIN * CAP1];   // 62.7 KB
    __shared__ int c1[NBIN];

    const int ch = blockIdx.x;
    const int t  = threadIdx.x;
    for (int i = t; i < NBIN; i += 256) c1[i] = 0;
    __syncthreads();

    const int e0 = ch * CH_E;
    const int e1 = (e0 + CH_E < N_EDGES) ? e0 + CH_E : N_EDGES;
    for (int e = e0 + t; e < e1; e += 256) {
        int d = dst[e];
        int s = src[e];
        int b = d >> BINSHIFT;
        int pos = atomicAdd(&c1[b], 1);
        if (pos < CAP1)
            bl[b * CAP1 + pos] = ((unsigned)s << BINSHIFT) | (unsigned)(d & (BINSZ - 1));
    }
    __syncthreads();

    const int wv = t >> 6, ln = t & 63;
    for (int b = wv; b < NBIN; b += 4) {
        int n = c1[b]; n = n < CAP1 ? n : CAP1;
        unsigned* sp = &slab[((size_t)b * NCH + ch) * CAP1];
        for (int i = ln; i < n; i += 64) sp[i] = bl[b * CAP1 + i];
        if (ln == 0) gcnt[b * NCH + ch] = n;
    }
}

// ---------------- bin base scan (tiny) ----------------

__global__ void k_binscan(const int* __restrict__ gcnt, int* __restrict__ binbase) {
    __shared__ int T[NBIN];
    int t = threadIdx.x;
    if (t < NBIN) {
        int s = 0;
        for (int c = 0; c < NCH; ++c) s += gcnt[t * NCH + c];
        T[t] = s;
    }
    __syncthreads();
    if (t == 0) {
        int run = 0;
        for (int b = 0; b < NBIN; ++b) { binbase[b] = run; run += T[b]; }
        binbase[NBIN] = run;
    }
}

// ---------------- CSR build pass 2: per-bin finalize, latency-parallel ----------------

__global__ __launch_bounds__(1024) void k_p2(const unsigned* __restrict__ slab,
                                             const int* __restrict__ gcnt,
                                             const int* __restrict__ binbase,
                                             int* __restrict__ csr_src,
                                             int* __restrict__ offs,
                                             float* __restrict__ dinv) {
    __shared__ unsigned eb[CAP2];          // 72 KB
    __shared__ int cnt2[BINSZ];
    __shared__ int off2[BINSZ];
    __shared__ int cur[BINSZ];
    __shared__ int choff[NCH + 1];
    __shared__ int csc[256];

    const int bin = blockIdx.x;
    const int t   = threadIdx.x;

    cnt2[t] = 0; cur[t] = 0;               // blockDim == BINSZ == 1024
    if (t < 256) csc[t] = (t < NCH) ? gcnt[bin * NCH + t] : 0;
    __syncthreads();

    for (int off = 1; off < 256; off <<= 1) {
        int add = 0;
        if (t < 256 && t >= off) add = csc[t - off];
        __syncthreads();
        if (t < 256) csc[t] += add;
        __syncthreads();
    }
    if (t < NCH) {
        int v = gcnt[bin * NCH + t];
        choff[t] = csc[t] - v;             // exclusive
        if (t == NCH - 1) choff[NCH] = csc[t];
    }
    __syncthreads();
    int total = choff[NCH]; total = total < CAP2 ? total : CAP2;

    const int wv = t >> 6, ln = t & 63;
    for (int c = wv; c < NCH; c += 16) {
        int o = choff[c];
        int n = choff[c + 1] - o;
        const unsigned* sp = &slab[((size_t)bin * NCH + c) * CAP1];
        for (int i = ln; i < n; i += 64) {
            int idx = o + i;
            if (idx < CAP2) {
                unsigned v = sp[i];
                eb[idx] = v;
                atomicAdd(&cnt2[v & (BINSZ - 1)], 1);
            }
        }
    }
    __syncthreads();

    int mycnt = cnt2[t];
    off2[t] = mycnt;
    __syncthreads();
    for (int off = 1; off < BINSZ; off <<= 1) {
        int add = (t >= off) ? off2[t - off] : 0;
        __syncthreads();
        off2[t] += add;
        __syncthreads();
    }
    int excl = off2[t] - mycnt;
    __syncthreads();
    off2[t] = excl;
    __syncthreads();

    const int base  = binbase[bin];
    const int node0 = bin << BINSHIFT;
    int node = node0 + t;
    if (node < N_NODES) {
        offs[node] = base + excl;
        dinv[node] = rsqrtf((float)(mycnt + 1));   // +1 self-loop
    }
    if (bin == NBIN - 1 && t == 0) offs[N_NODES] = base + total;
    __syncthreads();

    for (int i = t; i < total; i += 1024) {
        unsigned v = eb[i];
        int lo = v & (BINSZ - 1);
        int p = atomicAdd(&cur[lo], 1);
        csr_src[base + off2[lo] + p] = (int)(v >> BINSHIFT);
    }
}

// ---------------- W prep: Wt[l][c][k] = bf16(W[l][k][c]) (once) ----------------

__global__ __launch_bounds__(256) void k_wprep(const float* __restrict__ Ws,
                                               unsigned short* __restrict__ Wt_g) {
    int idx = blockIdx.x * 256 + threadIdx.x;
    if (idx >= 2 * HIDDEN * HIDDEN) return;
    int l = idx >> 14, rem = idx & 16383, c = rem >> 7, k = rem & 127;
    Wt_g[idx] = f2bf(Ws[l * HIDDEN * HIDDEN + k * HIDDEN + c]);
}

// ---------------- MFMA GEMM: Hb8 = fp8(8 * dinv ⊙ (X @ W)) ----------------
// 128x128 tile per 256-thread block (4 waves). X and Wt staged in LDS as bf16
// (pitch 136 -> 2-way-free b128 reads). Wave w owns rows w*32..w*32+31;
// 64x mfma_f32_16x16x32_bf16 per wave. fp8 epilogue repacked via LDS (aliases
// the dead X tile) so global stores stay 16B-coalesced.

template <bool IN_F32>
__global__ __launch_bounds__(256) void k_gemm(const void* __restrict__ Xin,
                                              const unsigned short* __restrict__ Wt_g,
                                              const float* __restrict__ dinv,
                                              unsigned char* __restrict__ Hb8) {
    __shared__ char sm[70144];
    unsigned short* Xl = (unsigned short*)sm;            // [128][136] bf16, 34816 B
    unsigned short* Wl = (unsigned short*)(sm + 34816);  // [128][136] bf16, 34816 B
    float*          Dl = (float*)(sm + 69632);           // [128] f32 (survives epilogue)
    unsigned char*  Hl = (unsigned char*)sm;             // [128][128] fp8 (aliases Xl)

    const int t    = threadIdx.x;
    const int row0 = blockIdx.x * 128;
    const float* Xf = (const float*)Xin;
    const unsigned short* Xb = (const unsigned short*)Xin;

    // ---- stage X (bf16), Wt (copy), dinv ----
    #pragma unroll
    for (int i = 0; i < 8; ++i) {
        int idx = t + i * 256;            // 2048 = 128 rows x 16 quads
        int r = idx >> 4, kq = idx & 15;
        int rg = row0 + r; rg = rg < N_NODES ? rg : N_NODES - 1;
        if (IN_F32) {
            float4 xa = *(const float4*)&Xf[(size_t)rg * HIDDEN + kq * 8];
            float4 xb = *(const float4*)&Xf[(size_t)rg * HIDDEN + kq * 8 + 4];
            unsigned short o[8];
            o[0] = f2bf(xa.x); o[1] = f2bf(xa.y); o[2] = f2bf(xa.z); o[3] = f2bf(xa.w);
            o[4] = f2bf(xb.x); o[5] = f2bf(xb.y); o[6] = f2bf(xb.z); o[7] = f2bf(xb.w);
            *(uint4*)&Xl[r * 136 + kq * 8] = *(uint4*)o;
        } else {
            *(uint4*)&Xl[r * 136 + kq * 8] = *(const uint4*)&Xb[(size_t)rg * HIDDEN + kq * 8];
        }
        *(uint4*)&Wl[r * 136 + kq * 8] = *(const uint4*)&Wt_g[r * HIDDEN + kq * 8];
    }
    if (t < 128) {
        int rg = row0 + t; rg = rg < N_NODES ? rg : N_NODES - 1;
        Dl[t] = dinv[rg] * 8.f;           // encode pre-scale folded in
    }
    __syncthreads();

    // ---- MFMA compute ----
    const int lane = t & 63;
    const int wv   = t >> 6;
    const int rb0  = wv * 32;
    const int arow = lane & 15;
    const int kgrp = lane >> 4;

    f32x4v c[2][8];
    #pragma unroll
    for (int rb = 0; rb < 2; ++rb)
        #pragma unroll
        for (int cb = 0; cb < 8; ++cb)
            c[rb][cb] = (f32x4v){0.f, 0.f, 0.f, 0.f};

    #pragma unroll
    for (int kc = 0; kc < 4; ++kc) {
        int kbase = kc * 32 + kgrp * 8;
        bf16x8 a0 = *(const bf16x8*)&Xl[(rb0 + arow) * 136 + kbase];
        bf16x8 a1 = *(const bf16x8*)&Xl[(rb0 + 16 + arow) * 136 + kbase];
        #pragma unroll
        for (int cb = 0; cb < 8; ++cb) {
            bf16x8 b = *(const bf16x8*)&Wl[(cb * 16 + arow) * 136 + kbase];
            c[0][cb] = __builtin_amdgcn_mfma_f32_16x16x32_bf16(a0, b, c[0][cb], 0, 0, 0);
            c[1][cb] = __builtin_amdgcn_mfma_f32_16x16x32_bf16(a1, b, c[1][cb], 0, 0, 0);
        }
    }
    __syncthreads();   // all LDS reads done; Xl region now reusable as Hl

    // ---- fp8 epilogue via LDS repack ----
    const int col   = lane & 15;
    const int rbase = (lane >> 4) * 4;
    #pragma unroll
    for (int rb = 0; rb < 2; ++rb) {
        #pragma unroll
        for (int cb = 0; cb < 8; ++cb) {
            int rl = rb0 + rb * 16 + rbase;
            f32x4v cv = c[rb][cb];
            unsigned p = enc4_e4m3(cv[0] * Dl[rl], cv[1] * Dl[rl + 1],
                                   cv[2] * Dl[rl + 2], cv[3] * Dl[rl + 3]);
            int cc = cb * 16 + col;
            Hl[(rl + 0) * 128 + cc] = (unsigned char)(p & 0xFF);
            Hl[(rl + 1) * 128 + cc] = (unsigned char)((p >> 8) & 0xFF);
            Hl[(rl + 2) * 128 + cc] = (unsigned char)((p >> 16) & 0xFF);
            Hl[(rl + 3) * 128 + cc] = (unsigned char)((p >> 24) & 0xFF);
        }
    }
    __syncthreads();

    #pragma unroll
    for (int i = 0; i < 4; ++i) {
        int q = t + i * 256;              // 1024 quads of 16B
        int r = q >> 3, qq = q & 7;
        int row = row0 + r;
        if (row < N_NODES)
            *(uint4*)&Hb8[(size_t)row * HIDDEN + qq * 16] = *(const uint4*)&Hl[r * 128 + qq * 16];
    }
}

// ---------------- fused aggregation over pre-scaled fp8 rows ----------------
// OUT_MODE: 0 = f32, 1 = fp8 (scaled by dinv*out_enc), 2 = bf16

template <int OUT_MODE, bool BIAS, bool RELU>
__global__ __launch_bounds__(256) void k_aggregate(const unsigned char* __restrict__ Hb8,
                                                   const int* __restrict__ offs,
                                                   const int* __restrict__ csr_src,
                                                   const float* __restrict__ dinv,
                                                   const float* __restrict__ bias,
                                                   void* __restrict__ outv,
                                                   float in_dec, float out_enc) {
    int g    = threadIdx.x >> 5;       // node-in-block 0..7
    int lane = threadIdx.x & 31;
    int node = blockIdx.x * 8 + g;
    if (node >= N_NODES) return;
    int c4 = lane * 4;

    float di = dinv[node];
    float4 acc = dec4_e4m3(*(const unsigned*)&Hb8[(size_t)node * HIDDEN + c4]);

    int j0 = offs[node], j1 = offs[node + 1];
    #pragma unroll 4
    for (int j = j0; j < j1; ++j) {
        int s = csr_src[j];
        float4 v = dec4_e4m3(*(const unsigned*)&Hb8[(size_t)s * HIDDEN + c4]);
        acc.x += v.x; acc.y += v.y; acc.z += v.z; acc.w += v.w;
    }

    float ms = di * in_dec;
    acc.x *= ms; acc.y *= ms; acc.z *= ms; acc.w *= ms;
    if (BIAS) {
        float4 bv = *(const float4*)&bias[c4];
        acc.x += bv.x; acc.y += bv.y; acc.z += bv.z; acc.w += bv.w;
    }
    if (RELU) {
        acc.x = fmaxf(acc.x, 0.f); acc.y = fmaxf(acc.y, 0.f);
        acc.z = fmaxf(acc.z, 0.f); acc.w = fmaxf(acc.w, 0.f);
    }
    if (OUT_MODE == 1) {
        float es = di * out_enc;
        unsigned p = enc4_e4m3(acc.x * es, acc.y * es, acc.z * es, acc.w * es);
        *(unsigned*)&((unsigned char*)outv)[(size_t)node * HIDDEN + c4] = p;
    } else if (OUT_MODE == 2) {
        ushort4 o;
        o.x = f2bf(acc.x); o.y = f2bf(acc.y); o.z = f2bf(acc.z); o.w = f2bf(acc.w);
        *(ushort4*)&((unsigned short*)outv)[(size_t)node * HIDDEN + c4] = o;
    } else {
        *(float4*)&((float*)outv)[(size_t)node * HIDDEN + c4] = acc;
    }
}

// ---------------- pooling: segmented reduction, no atomics ----------------

__global__ __launch_bounds__(256) void k_pool2(const float* __restrict__ X,
                                               const int* __restrict__ gstart,
                                               float* __restrict__ part) {
    int g  = blockIdx.x;
    int ch = blockIdx.y;
    int start = gstart[g], end = gstart[g + 1];
    int len = end - start;
    int r0 = start + (int)((long long)len * ch / POOL_CHUNKS);
    int r1 = start + (int)((long long)len * (ch + 1) / POOL_CHUNKS);

    int rp = threadIdx.x >> 5;         // 0..7 rows in parallel
    int c4 = (threadIdx.x & 31) * 4;

    float4 acc = make_float4(0.f, 0.f, 0.f, 0.f);
    for (int r = r0 + rp; r < r1; r += 8) {
        float4 v = *(const float4*)&X[(size_t)r * HIDDEN + c4];
        acc.x += v.x; acc.y += v.y; acc.z += v.z; acc.w += v.w;
    }

    __shared__ float4 sh[256];
    sh[threadIdx.x] = acc;
    __syncthreads();
    #pragma unroll
    for (int off = 4; off >= 1; off >>= 1) {
        if (rp < off) {
            float4 o = sh[(rp + off) * 32 + (threadIdx.x & 31)];
            float4 m = sh[threadIdx.x];
            m.x += o.x; m.y += o.y; m.z += o.z; m.w += o.w;
            sh[threadIdx.x] = m;
        }
        __syncthreads();
    }
    if (rp == 0) {
        float4 v = sh[threadIdx.x];
        *(float4*)&part[((size_t)g * POOL_CHUNKS + ch) * HIDDEN + c4] = v;
    }
}

// ---------------- final: out = ((Σpart/cnt) @ W2 + b2) @ linW + linb ----------------

__global__ void k_final(const float* __restrict__ part, const int* __restrict__ gstart,
                        const float* __restrict__ W2, const float* __restrict__ b2,
                        const float* __restrict__ linW, const float* __restrict__ linb,
                        float* __restrict__ out) {
    __shared__ float m[HIDDEN];
    __shared__ float t[HIDDEN];
    int g = blockIdx.x;
    int c = threadIdx.x;
    float s = 0.f;
    #pragma unroll
    for (int ch = 0; ch < POOL_CHUNKS; ++ch)
        s += part[((size_t)g * POOL_CHUNKS + ch) * HIDDEN + c];
    float cnt = fmaxf((float)(gstart[g + 1] - gstart[g]), 1.0f);
    m[c] = s / cnt;
    __syncthreads();
    float acc = b2[c];
    #pragma unroll 4
    for (int k = 0; k < HIDDEN; ++k) acc += m[k] * W2[k * HIDDEN + c];
    t[c] = acc;
    __syncthreads();
    if (c < 16) {
        float o = linb[c];
        #pragma unroll 4
        for (int k = 0; k < HIDDEN; ++k) o += t[k] * linW[k * 16 + c];
        out[g * 16 + c] = o;
    }
}

// ---------------- launch ----------------

extern "C" void kernel_launch(void* const* d_in, const int* in_sizes, int n_in,
                              void* d_out, int out_size, void* d_ws, size_t ws_size,
                              hipStream_t stream) {
    const float* x     = (const float*)d_in[0];
    const int*   edge  = (const int*)d_in[1];   // [2, E] flat
    const int*   batch = (const int*)d_in[2];
    const float* Ws    = (const float*)d_in[3]; // [3,128,128]
    const float* bs    = (const float*)d_in[4]; // [3,128]
    const float* linW  = (const float*)d_in[5]; // [128,16]
    const float* linb  = (const float*)d_in[6]; // [16]
    float* out = (float*)d_out;

    const int* src = edge;
    const int* dst = edge + N_EDGES;

    // workspace layout
    float* bufA = (float*)d_ws;                       // N*128 fp32 (x3 for pool)
    unsigned* slab = (unsigned*)bufA;                 // CSR-build scratch (12.3MB), dead before agg writes bufA
    float* bufBreg = bufA + (size_t)N_NODES * HIDDEN; // N*128 fp32-sized region, carved:
    unsigned char* hb8  = (unsigned char*)bufBreg;                                    // [0, 12.8MB)
    unsigned char* x2b8 = (unsigned char*)bufBreg + (size_t)N_NODES * HIDDEN;         // [12.8, 25.6MB)
    unsigned short* x1b = (unsigned short*)((unsigned char*)bufBreg + (size_t)2 * N_NODES * HIDDEN); // [25.6, 51.2MB) bf16
    float* dinv = bufBreg + (size_t)N_NODES * HIDDEN; // N (at 51.2MB offset)
    float* part = dinv + N_NODES;                     // 64*16*128
    int* offs    = (int*)(part + NUM_GRAPHS * POOL_CHUNKS * HIDDEN); // N+1
    int* csr_src = offs + N_NODES + 1;                // E
    int* gstart  = csr_src + N_EDGES;                 // NUM_GRAPHS+1
    int* gcnt    = gstart + NUM_GRAPHS + 1;           // NBIN*NCH
    int* binbase = gcnt + NBIN * NCH;                 // NBIN+1
    unsigned short* Wt_g = (unsigned short*)(binbase + NBIN + 1); // 2*128*128 bf16 (64KB)

    const int NB_N    = (N_NODES + 255) / 256;   // 391
    const int NB_ROW  = N_NODES / 8;             // 12500
    const int NB_GEMM = (N_NODES + 127) / 128;   // 782

    // CSR build (also produces offs, dinv) — LDS-staged, no global atomics
    k_p1<<<NCH, 256, 0, stream>>>(src, dst, slab, gcnt);
    k_binscan<<<1, 128, 0, stream>>>(gcnt, binbase);
    k_p2<<<NBIN, 1024, 0, stream>>>(slab, gcnt, binbase, csr_src, offs, dinv);
    k_gbounds<<<NB_N, 256, 0, stream>>>(batch, gstart);
    k_wprep<<<(2 * HIDDEN * HIDDEN + 255) / 256, 256, 0, stream>>>(Ws, Wt_g);

    // layer 0: hb8 = fp8(8*dinv*(x@W0)) ; x1b = bf16(relu(dinv*Σ/8 + b0))
    k_gemm<true><<<NB_GEMM, 256, 0, stream>>>(x, Wt_g, dinv, hb8);
    k_aggregate<2, true, true><<<NB_ROW, 256, 0, stream>>>(hb8, offs, csr_src, dinv, bs, x1b, 0.125f, 0.f);

    // layer 1: hb8 = fp8(8*dinv*(x1@W1)) ; x2' = fp8(32*dinv*relu(dinv*Σ/8 + b1))
    k_gemm<false><<<NB_GEMM, 256, 0, stream>>>(x1b, Wt_g + HIDDEN * HIDDEN, dinv, hb8);
    k_aggregate<1, true, true><<<NB_ROW, 256, 0, stream>>>(hb8, offs, csr_src, dinv, bs + HIDDEN, x2b8, 0.125f, 32.f);

    // layer 2 (algebraic trick): x3 = dinv*Σ/32 ; pool ; tiny GEMMs in k_final
    k_aggregate<0, false, false><<<NB_ROW, 256, 0, stream>>>(x2b8, offs, csr_src, dinv, nullptr, bufA, 0.03125f, 0.f);
    k_pool2<<<dim3(NUM_GRAPHS, POOL_CHUNKS), 256, 0, stream>>>(bufA, gstart, part);

    k_final<<<NUM_GRAPHS, HIDDEN, 0, stream>>>(part, gstart,
                                               Ws + 2 * HIDDEN * HIDDEN, bs + 2 * HIDDEN,
                                               linW, linb, out);
}

// Round 12
// 220.737 us; speedup vs baseline: 2.1785x; 1.1230x over previous
//
#include <hip/hip_runtime.h>
#include <math.h>

#define N_NODES    100000
#define N_EDGES    1600000
#define HIDDEN     128
#define NUM_GRAPHS 64

constexpr int POOL_CHUNKS = 16;

// ---- two-level LDS-staged CSR build ----
constexpr int BINSHIFT = 10;
constexpr int BINSZ    = 1 << BINSHIFT;                  // 1024 nodes per bin
constexpr int NBIN     = (N_NODES + BINSZ - 1) / BINSZ;  // 98
constexpr int CH_E     = 8192;                           // edges per chunk
constexpr int NCH      = (N_EDGES + CH_E - 1) / CH_E;    // 196
constexpr int CAP1     = 160;  // per (bin,chunk): mean 84, +8.3 sigma
constexpr int CAP2     = 18432; // per bin: mean 16384, +16 sigma

// ---------------- bf16 helpers ----------------

static __device__ __forceinline__ unsigned short f2bf(float f) {
    unsigned u = __float_as_uint(f);
    u += 0x7FFFu + ((u >> 16) & 1u);
    return (unsigned short)(u >> 16);
}
static __device__ __forceinline__ float b2f(unsigned short h) {
    return __uint_as_float(((unsigned)h) << 16);
}

// ---------------- fp8 e4m3fn helpers (OCP, native on gfx950) ----------------

typedef float floatx2 __attribute__((ext_vector_type(2)));
typedef short bf16x8  __attribute__((ext_vector_type(8)));
typedef float f32x4v  __attribute__((ext_vector_type(4)));

#if __has_builtin(__builtin_amdgcn_cvt_pk_f32_fp8) && __has_builtin(__builtin_amdgcn_cvt_pk_fp8_f32)
#define FP8_HW 1
#else
#define FP8_HW 0
#endif

static __device__ __forceinline__ float4 dec4_e4m3(unsigned u) {
#if FP8_HW
    floatx2 lo = __builtin_amdgcn_cvt_pk_f32_fp8((int)u, false);
    floatx2 hi = __builtin_amdgcn_cvt_pk_f32_fp8((int)u, true);
    return make_float4(lo[0], lo[1], hi[0], hi[1]);
#else
    float t[4];
    #pragma unroll
    for (int i = 0; i < 4; ++i) {
        unsigned x = (u >> (8 * i)) & 0xFFu;
        unsigned s = x >> 7, e = (x >> 3) & 15u, m = x & 7u;
        float fn = __uint_as_float((s << 31) | ((e + 120u) << 23) | (m << 20));
        float fs = (float)m * 0.001953125f;
        if (s) fs = -fs;
        t[i] = e ? fn : fs;
    }
    return make_float4(t[0], t[1], t[2], t[3]);
#endif
}

static __device__ __forceinline__ unsigned char enc1_e4m3(float v) {
    unsigned u = __float_as_uint(v);
    unsigned s = u >> 31;
    float a = fabsf(v);
    if (a >= 448.f) return (unsigned char)((s << 7) | 0x7Eu);
    if (a < 0.015625f) {
        unsigned q = (unsigned)rintf(a * 512.f);
        return (unsigned char)((s << 7) | q);
    }
    unsigned au = u & 0x7FFFFFFFu;
    au += 0x7FFFFu + ((au >> 20) & 1u);
    unsigned e = (au >> 23) - 120u;
    unsigned m = (au >> 20) & 7u;
    if (e >= 15u && m >= 7u) { e = 15u; m = 6u; }
    return (unsigned char)((s << 7) | (e << 3) | m);
}

static __device__ __forceinline__ unsigned enc4_e4m3(float a, float b, float c, float d) {
#if FP8_HW
    int v = 0;
    v = __builtin_amdgcn_cvt_pk_fp8_f32(a, b, v, false);
    v = __builtin_amdgcn_cvt_pk_fp8_f32(c, d, v, true);
    return (unsigned)v;
#else
    return (unsigned)enc1_e4m3(a) | ((unsigned)enc1_e4m3(b) << 8) |
           ((unsigned)enc1_e4m3(c) << 16) | ((unsigned)enc1_e4m3(d) << 24);
#endif
}

// ---------------- graph boundaries (batch is sorted) ----------------

__global__ void k_gbounds(const int* __restrict__ batch, int* __restrict__ gstart) {
    int i = blockIdx.x * blockDim.x + threadIdx.x;
    if (i >= N_NODES) return;
    int b = batch[i];
    if (i == 0) {
        for (int g = 0; g <= b; ++g) gstart[g] = 0;
    } else {
        int bp = batch[i - 1];
        for (int g = bp + 1; g <= b; ++g) gstart[g] = i;
    }
    if (i == N_NODES - 1) {
        for (int g = b + 1; g <= NUM_GRAPHS; ++g) gstart[g] = N_NODES;
    }
}

// ---------------- CSR build pass 1: LDS-binned, full-line flush ----------------

__global__ __launch_bounds__(256) void k_p1(const int* __restrict__ src,
                                            const int* __restrict__ dst,
                                            unsigned* __restrict__ slab,
                                            int* __restrict__ gcnt) {
    __shared__ unsigned bl[NBIN * CAP1];   // 62.7 KB
    __shared__ int c1[NBIN];

    const int ch = blockIdx.x;
    const int t  = threadIdx.x;
    for (int i = t; i < NBIN; i += 256) c1[i] = 0;
    __syncthreads();

    const int e0 = ch * CH_E;
    const int e1 = (e0 + CH_E < N_EDGES) ? e0 + CH_E : N_EDGES;
    for (int e = e0 + t; e < e1; e += 256) {
        int d = dst[e];
        int s = src[e];
        int b = d >> BINSHIFT;
        int pos = atomicAdd(&c1[b], 1);
        if (pos < CAP1)
            bl[b * CAP1 + pos] = ((unsigned)s << BINSHIFT) | (unsigned)(d & (BINSZ - 1));
    }
    __syncthreads();

    const int wv = t >> 6, ln = t & 63;
    for (int b = wv; b < NBIN; b += 4) {
        int n = c1[b]; n = n < CAP1 ? n : CAP1;
        unsigned* sp = &slab[((size_t)b * NCH + ch) * CAP1];
        for (int i = ln; i < n; i += 64) sp[i] = bl[b * CAP1 + i];
        if (ln == 0) gcnt[b * NCH + ch] = n;
    }
}

// ---------------- bin base scan (tiny) ----------------

__global__ void k_binscan(const int* __restrict__ gcnt, int* __restrict__ binbase) {
    __shared__ int T[NBIN];
    int t = threadIdx.x;
    if (t < NBIN) {
        int s = 0;
        for (int c = 0; c < NCH; ++c) s += gcnt[t * NCH + c];
        T[t] = s;
    }
    __syncthreads();
    if (t == 0) {
        int run = 0;
        for (int b = 0; b < NBIN; ++b) { binbase[b] = run; run += T[b]; }
        binbase[NBIN] = run;
    }
}

// ---------------- CSR build pass 2: per-bin finalize, latency-parallel ----------------

__global__ __launch_bounds__(1024) void k_p2(const unsigned* __restrict__ slab,
                                             const int* __restrict__ gcnt,
                                             const int* __restrict__ binbase,
                                             int* __restrict__ csr_src,
                                             int* __restrict__ offs,
                                             float* __restrict__ dinv) {
    __shared__ unsigned eb[CAP2];          // 72 KB
    __shared__ int cnt2[BINSZ];
    __shared__ int off2[BINSZ];
    __shared__ int cur[BINSZ];
    __shared__ int choff[NCH + 1];
    __shared__ int csc[256];

    const int bin = blockIdx.x;
    const int t   = threadIdx.x;

    cnt2[t] = 0; cur[t] = 0;               // blockDim == BINSZ == 1024
    if (t < 256) csc[t] = (t < NCH) ? gcnt[bin * NCH + t] : 0;
    __syncthreads();

    for (int off = 1; off < 256; off <<= 1) {
        int add = 0;
        if (t < 256 && t >= off) add = csc[t - off];
        __syncthreads();
        if (t < 256) csc[t] += add;
        __syncthreads();
    }
    if (t < NCH) {
        int v = gcnt[bin * NCH + t];
        choff[t] = csc[t] - v;             // exclusive
        if (t == NCH - 1) choff[NCH] = csc[t];
    }
    __syncthreads();
    int total = choff[NCH]; total = total < CAP2 ? total : CAP2;

    const int wv = t >> 6, ln = t & 63;
    for (int c = wv; c < NCH; c += 16) {
        int o = choff[c];
        int n = choff[c + 1] - o;
        const unsigned* sp = &slab[((size_t)bin * NCH + c) * CAP1];
        for (int i = ln; i < n; i += 64) {
            int idx = o + i;
            if (idx < CAP2) {
                unsigned v = sp[i];
                eb[idx] = v;
                atomicAdd(&cnt2[v & (BINSZ - 1)], 1);
            }
        }
    }
    __syncthreads();

    int mycnt = cnt2[t];
    off2[t] = mycnt;
    __syncthreads();
    for (int off = 1; off < BINSZ; off <<= 1) {
        int add = (t >= off) ? off2[t - off] : 0;
        __syncthreads();
        off2[t] += add;
        __syncthreads();
    }
    int excl = off2[t] - mycnt;
    __syncthreads();
    off2[t] = excl;
    __syncthreads();

    const int base  = binbase[bin];
    const int node0 = bin << BINSHIFT;
    int node = node0 + t;
    if (node < N_NODES) {
        offs[node] = base + excl;
        dinv[node] = rsqrtf((float)(mycnt + 1));   // +1 self-loop
    }
    if (bin == NBIN - 1 && t == 0) offs[N_NODES] = base + total;
    __syncthreads();

    for (int i = t; i < total; i += 1024) {
        unsigned v = eb[i];
        int lo = v & (BINSZ - 1);
        int p = atomicAdd(&cur[lo], 1);
        csr_src[base + off2[lo] + p] = (int)(v >> BINSHIFT);
    }
}

// ---------------- W prep: Wt[l][c][k] = bf16(W[l][k][c]) (once) ----------------

__global__ __launch_bounds__(256) void k_wprep(const float* __restrict__ Ws,
                                               unsigned short* __restrict__ Wt_g) {
    int idx = blockIdx.x * 256 + threadIdx.x;
    if (idx >= 2 * HIDDEN * HIDDEN) return;
    int l = idx >> 14, rem = idx & 16383, c = rem >> 7, k = rem & 127;
    Wt_g[idx] = f2bf(Ws[l * HIDDEN * HIDDEN + k * HIDDEN + c]);
}

// ---------------- MFMA GEMM: Hb8 = fp8(8 * dinv ⊙ (X @ W)) ----------------

template <bool IN_F32>
__global__ __launch_bounds__(256) void k_gemm(const void* __restrict__ Xin,
                                              const unsigned short* __restrict__ Wt_g,
                                              const float* __restrict__ dinv,
                                              unsigned char* __restrict__ Hb8) {
    __shared__ char sm[70144];
    unsigned short* Xl = (unsigned short*)sm;            // [128][136] bf16
    unsigned short* Wl = (unsigned short*)(sm + 34816);  // [128][136] bf16
    float*          Dl = (float*)(sm + 69632);           // [128] f32
    unsigned char*  Hl = (unsigned char*)sm;             // [128][128] fp8 (aliases Xl)

    const int t    = threadIdx.x;
    const int row0 = blockIdx.x * 128;
    const float* Xf = (const float*)Xin;
    const unsigned short* Xb = (const unsigned short*)Xin;

    #pragma unroll
    for (int i = 0; i < 8; ++i) {
        int idx = t + i * 256;
        int r = idx >> 4, kq = idx & 15;
        int rg = row0 + r; rg = rg < N_NODES ? rg : N_NODES - 1;
        if (IN_F32) {
            float4 xa = *(const float4*)&Xf[(size_t)rg * HIDDEN + kq * 8];
            float4 xb = *(const float4*)&Xf[(size_t)rg * HIDDEN + kq * 8 + 4];
            unsigned short o[8];
            o[0] = f2bf(xa.x); o[1] = f2bf(xa.y); o[2] = f2bf(xa.z); o[3] = f2bf(xa.w);
            o[4] = f2bf(xb.x); o[5] = f2bf(xb.y); o[6] = f2bf(xb.z); o[7] = f2bf(xb.w);
            *(uint4*)&Xl[r * 136 + kq * 8] = *(uint4*)o;
        } else {
            *(uint4*)&Xl[r * 136 + kq * 8] = *(const uint4*)&Xb[(size_t)rg * HIDDEN + kq * 8];
        }
        *(uint4*)&Wl[r * 136 + kq * 8] = *(const uint4*)&Wt_g[r * HIDDEN + kq * 8];
    }
    if (t < 128) {
        int rg = row0 + t; rg = rg < N_NODES ? rg : N_NODES - 1;
        Dl[t] = dinv[rg] * 8.f;
    }
    __syncthreads();

    const int lane = t & 63;
    const int wv   = t >> 6;
    const int rb0  = wv * 32;
    const int arow = lane & 15;
    const int kgrp = lane >> 4;

    f32x4v c[2][8];
    #pragma unroll
    for (int rb = 0; rb < 2; ++rb)
        #pragma unroll
        for (int cb = 0; cb < 8; ++cb)
            c[rb][cb] = (f32x4v){0.f, 0.f, 0.f, 0.f};

    #pragma unroll
    for (int kc = 0; kc < 4; ++kc) {
        int kbase = kc * 32 + kgrp * 8;
        bf16x8 a0 = *(const bf16x8*)&Xl[(rb0 + arow) * 136 + kbase];
        bf16x8 a1 = *(const bf16x8*)&Xl[(rb0 + 16 + arow) * 136 + kbase];
        #pragma unroll
        for (int cb = 0; cb < 8; ++cb) {
            bf16x8 b = *(const bf16x8*)&Wl[(cb * 16 + arow) * 136 + kbase];
            c[0][cb] = __builtin_amdgcn_mfma_f32_16x16x32_bf16(a0, b, c[0][cb], 0, 0, 0);
            c[1][cb] = __builtin_amdgcn_mfma_f32_16x16x32_bf16(a1, b, c[1][cb], 0, 0, 0);
        }
    }
    __syncthreads();

    const int col   = lane & 15;
    const int rbase = (lane >> 4) * 4;
    #pragma unroll
    for (int rb = 0; rb < 2; ++rb) {
        #pragma unroll
        for (int cb = 0; cb < 8; ++cb) {
            int rl = rb0 + rb * 16 + rbase;
            f32x4v cv = c[rb][cb];
            unsigned p = enc4_e4m3(cv[0] * Dl[rl], cv[1] * Dl[rl + 1],
                                   cv[2] * Dl[rl + 2], cv[3] * Dl[rl + 3]);
            int cc = cb * 16 + col;
            Hl[(rl + 0) * 128 + cc] = (unsigned char)(p & 0xFF);
            Hl[(rl + 1) * 128 + cc] = (unsigned char)((p >> 8) & 0xFF);
            Hl[(rl + 2) * 128 + cc] = (unsigned char)((p >> 16) & 0xFF);
            Hl[(rl + 3) * 128 + cc] = (unsigned char)((p >> 24) & 0xFF);
        }
    }
    __syncthreads();

    #pragma unroll
    for (int i = 0; i < 4; ++i) {
        int q = t + i * 256;
        int r = q >> 3, qq = q & 7;
        int row = row0 + r;
        if (row < N_NODES)
            *(uint4*)&Hb8[(size_t)row * HIDDEN + qq * 16] = *(const uint4*)&Hl[r * 128 + qq * 16];
    }
}

// ---------------- fused aggregation over pre-scaled fp8 rows ----------------
// 16 lanes per node (dwordx2/lane) -> 4 rows per wave per load instr; dual
// accumulators process 2 edges/iter -> ~4 lines in flight per lane-group.
// OUT_MODE: 0 = f32, 1 = fp8 (scaled by dinv*out_enc), 2 = bf16

template <int OUT_MODE, bool BIAS, bool RELU>
__global__ __launch_bounds__(256) void k_aggregate(const unsigned char* __restrict__ Hb8,
                                                   const int* __restrict__ offs,
                                                   const int* __restrict__ csr_src,
                                                   const float* __restrict__ dinv,
                                                   const float* __restrict__ bias,
                                                   void* __restrict__ outv,
                                                   float in_dec, float out_enc) {
    int g    = threadIdx.x >> 4;       // node-in-block 0..15
    int lane = threadIdx.x & 15;       // 16 lanes per node
    int node = blockIdx.x * 16 + g;
    if (node >= N_NODES) return;
    int c8 = lane * 8;                 // 8 fp8 columns per lane

    float di = dinv[node];
    float accA[8], accB[8];
    {
        uint2 sv = *(const uint2*)&Hb8[(size_t)node * HIDDEN + c8];
        float4 s0 = dec4_e4m3(sv.x), s1 = dec4_e4m3(sv.y);
        accA[0] = s0.x; accA[1] = s0.y; accA[2] = s0.z; accA[3] = s0.w;
        accA[4] = s1.x; accA[5] = s1.y; accA[6] = s1.z; accA[7] = s1.w;
        #pragma unroll
        for (int i = 0; i < 8; ++i) accB[i] = 0.f;
    }

    int j0 = offs[node], j1 = offs[node + 1];
    int j = j0;
    #pragma unroll 2
    for (; j + 2 <= j1; j += 2) {
        int s0 = csr_src[j], s1 = csr_src[j + 1];
        uint2 v0 = *(const uint2*)&Hb8[(size_t)s0 * HIDDEN + c8];
        uint2 v1 = *(const uint2*)&Hb8[(size_t)s1 * HIDDEN + c8];
        float4 a0 = dec4_e4m3(v0.x), a1 = dec4_e4m3(v0.y);
        float4 b0 = dec4_e4m3(v1.x), b1 = dec4_e4m3(v1.y);
        accA[0] += a0.x; accA[1] += a0.y; accA[2] += a0.z; accA[3] += a0.w;
        accA[4] += a1.x; accA[5] += a1.y; accA[6] += a1.z; accA[7] += a1.w;
        accB[0] += b0.x; accB[1] += b0.y; accB[2] += b0.z; accB[3] += b0.w;
        accB[4] += b1.x; accB[5] += b1.y; accB[6] += b1.z; accB[7] += b1.w;
    }
    if (j < j1) {
        int s0 = csr_src[j];
        uint2 v0 = *(const uint2*)&Hb8[(size_t)s0 * HIDDEN + c8];
        float4 a0 = dec4_e4m3(v0.x), a1 = dec4_e4m3(v0.y);
        accA[0] += a0.x; accA[1] += a0.y; accA[2] += a0.z; accA[3] += a0.w;
        accA[4] += a1.x; accA[5] += a1.y; accA[6] += a1.z; accA[7] += a1.w;
    }

    float ms = di * in_dec;
    float acc[8];
    #pragma unroll
    for (int i = 0; i < 8; ++i) acc[i] = (accA[i] + accB[i]) * ms;
    if (BIAS) {
        float4 b0 = *(const float4*)&bias[c8];
        float4 b1 = *(const float4*)&bias[c8 + 4];
        acc[0] += b0.x; acc[1] += b0.y; acc[2] += b0.z; acc[3] += b0.w;
        acc[4] += b1.x; acc[5] += b1.y; acc[6] += b1.z; acc[7] += b1.w;
    }
    if (RELU) {
        #pragma unroll
        for (int i = 0; i < 8; ++i) acc[i] = fmaxf(acc[i], 0.f);
    }
    if (OUT_MODE == 1) {
        float es = di * out_enc;
        uint2 p;
        p.x = enc4_e4m3(acc[0] * es, acc[1] * es, acc[2] * es, acc[3] * es);
        p.y = enc4_e4m3(acc[4] * es, acc[5] * es, acc[6] * es, acc[7] * es);
        *(uint2*)&((unsigned char*)outv)[(size_t)node * HIDDEN + c8] = p;
    } else if (OUT_MODE == 2) {
        unsigned short o[8];
        #pragma unroll
        for (int i = 0; i < 8; ++i) o[i] = f2bf(acc[i]);
        *(uint4*)&((unsigned short*)outv)[(size_t)node * HIDDEN + c8] = *(uint4*)o;
    } else {
        *(float4*)&((float*)outv)[(size_t)node * HIDDEN + c8]     = make_float4(acc[0], acc[1], acc[2], acc[3]);
        *(float4*)&((float*)outv)[(size_t)node * HIDDEN + c8 + 4] = make_float4(acc[4], acc[5], acc[6], acc[7]);
    }
}

// ---------------- pooling: segmented reduction over bf16 rows, no atomics ----------------

__global__ __launch_bounds__(256) void k_pool2(const unsigned short* __restrict__ X,
                                               const int* __restrict__ gstart,
                                               float* __restrict__ part) {
    int g  = blockIdx.x;
    int ch = blockIdx.y;
    int start = gstart[g], end = gstart[g + 1];
    int len = end - start;
    int r0 = start + (int)((long long)len * ch / POOL_CHUNKS);
    int r1 = start + (int)((long long)len * (ch + 1) / POOL_CHUNKS);

    int rp = threadIdx.x >> 5;         // 0..7 rows in parallel
    int c4 = (threadIdx.x & 31) * 4;

    float4 acc = make_float4(0.f, 0.f, 0.f, 0.f);
    for (int r = r0 + rp; r < r1; r += 8) {
        uint2 raw = *(const uint2*)&X[(size_t)r * HIDDEN + c4];
        acc.x += b2f((unsigned short)(raw.x & 0xFFFFu));
        acc.y += b2f((unsigned short)(raw.x >> 16));
        acc.z += b2f((unsigned short)(raw.y & 0xFFFFu));
        acc.w += b2f((unsigned short)(raw.y >> 16));
    }

    __shared__ float4 sh[256];
    sh[threadIdx.x] = acc;
    __syncthreads();
    #pragma unroll
    for (int off = 4; off >= 1; off >>= 1) {
        if (rp < off) {
            float4 o = sh[(rp + off) * 32 + (threadIdx.x & 31)];
            float4 m = sh[threadIdx.x];
            m.x += o.x; m.y += o.y; m.z += o.z; m.w += o.w;
            sh[threadIdx.x] = m;
        }
        __syncthreads();
    }
    if (rp == 0) {
        float4 v = sh[threadIdx.x];
        *(float4*)&part[((size_t)g * POOL_CHUNKS + ch) * HIDDEN + c4] = v;
    }
}

// ---------------- final: out = ((Σpart/cnt) @ W2 + b2) @ linW + linb ----------------

__global__ void k_final(const float* __restrict__ part, const int* __restrict__ gstart,
                        const float* __restrict__ W2, const float* __restrict__ b2,
                        const float* __restrict__ linW, const float* __restrict__ linb,
                        float* __restrict__ out) {
    __shared__ float m[HIDDEN];
    __shared__ float t[HIDDEN];
    int g = blockIdx.x;
    int c = threadIdx.x;
    float s = 0.f;
    #pragma unroll
    for (int ch = 0; ch < POOL_CHUNKS; ++ch)
        s += part[((size_t)g * POOL_CHUNKS + ch) * HIDDEN + c];
    float cnt = fmaxf((float)(gstart[g + 1] - gstart[g]), 1.0f);
    m[c] = s / cnt;
    __syncthreads();
    float acc = b2[c];
    #pragma unroll 4
    for (int k = 0; k < HIDDEN; ++k) acc += m[k] * W2[k * HIDDEN + c];
    t[c] = acc;
    __syncthreads();
    if (c < 16) {
        float o = linb[c];
        #pragma unroll 4
        for (int k = 0; k < HIDDEN; ++k) o += t[k] * linW[k * 16 + c];
        out[g * 16 + c] = o;
    }
}

// ---------------- launch ----------------

extern "C" void kernel_launch(void* const* d_in, const int* in_sizes, int n_in,
                              void* d_out, int out_size, void* d_ws, size_t ws_size,
                              hipStream_t stream) {
    const float* x     = (const float*)d_in[0];
    const int*   edge  = (const int*)d_in[1];   // [2, E] flat
    const int*   batch = (const int*)d_in[2];
    const float* Ws    = (const float*)d_in[3]; // [3,128,128]
    const float* bs    = (const float*)d_in[4]; // [3,128]
    const float* linW  = (const float*)d_in[5]; // [128,16]
    const float* linb  = (const float*)d_in[6]; // [16]
    float* out = (float*)d_out;

    const int* src = edge;
    const int* dst = edge + N_EDGES;

    // workspace layout
    float* bufA = (float*)d_ws;                       // CSR-build scratch region
    unsigned* slab = (unsigned*)bufA;                 // NBIN*NCH*CAP1 u32 (12.3MB), dead after p2
    float* bufBreg = bufA + (size_t)N_NODES * HIDDEN;
    unsigned char* hb8  = (unsigned char*)bufBreg;                                    // [0, 12.8MB) fp8
    unsigned char* x2b8 = (unsigned char*)bufBreg + (size_t)N_NODES * HIDDEN;         // [12.8, 25.6MB) fp8
    unsigned short* x1b = (unsigned short*)((unsigned char*)bufBreg + (size_t)2 * N_NODES * HIDDEN); // [25.6, 51.2MB) bf16 (x1, then x3)
    float* dinv = bufBreg + (size_t)N_NODES * HIDDEN; // N (at 51.2MB offset)
    float* part = dinv + N_NODES;                     // 64*16*128
    int* offs    = (int*)(part + NUM_GRAPHS * POOL_CHUNKS * HIDDEN); // N+1
    int* csr_src = offs + N_NODES + 1;                // E
    int* gstart  = csr_src + N_EDGES;                 // NUM_GRAPHS+1
    int* gcnt    = gstart + NUM_GRAPHS + 1;           // NBIN*NCH
    int* binbase = gcnt + NBIN * NCH;                 // NBIN+1
    unsigned short* Wt_g = (unsigned short*)(binbase + NBIN + 1); // 2*128*128 bf16 (64KB)

    const int NB_N    = (N_NODES + 255) / 256;   // 391
    const int NB_AGG  = N_NODES / 16;            // 6250 (16 nodes per 256-thr block)
    const int NB_GEMM = (N_NODES + 127) / 128;   // 782

    // CSR build (also produces offs, dinv) — LDS-staged, no global atomics
    k_p1<<<NCH, 256, 0, stream>>>(src, dst, slab, gcnt);
    k_binscan<<<1, 128, 0, stream>>>(gcnt, binbase);
    k_p2<<<NBIN, 1024, 0, stream>>>(slab, gcnt, binbase, csr_src, offs, dinv);
    k_gbounds<<<NB_N, 256, 0, stream>>>(batch, gstart);
    k_wprep<<<(2 * HIDDEN * HIDDEN + 255) / 256, 256, 0, stream>>>(Ws, Wt_g);

    // layer 0: hb8 = fp8(8*dinv*(x@W0)) ; x1b = bf16(relu(dinv*Σ/8 + b0))
    k_gemm<true><<<NB_GEMM, 256, 0, stream>>>(x, Wt_g, dinv, hb8);
    k_aggregate<2, true, true><<<NB_AGG, 256, 0, stream>>>(hb8, offs, csr_src, dinv, bs, x1b, 0.125f, 0.f);

    // layer 1: hb8 = fp8(8*dinv*(x1@W1)) ; x2' = fp8(32*dinv*relu(dinv*Σ/8 + b1))
    k_gemm<false><<<NB_GEMM, 256, 0, stream>>>(x1b, Wt_g + HIDDEN * HIDDEN, dinv, hb8);
    k_aggregate<1, true, true><<<NB_AGG, 256, 0, stream>>>(hb8, offs, csr_src, dinv, bs + HIDDEN, x2b8, 0.125f, 32.f);

    // layer 2 (algebraic trick): x3b = bf16(dinv*Σ/32) ; pool bf16 ; tiny GEMMs in k_final
    k_aggregate<2, false, false><<<NB_AGG, 256, 0, stream>>>(x2b8, offs, csr_src, dinv, nullptr, x1b, 0.03125f, 0.f);
    k_pool2<<<dim3(NUM_GRAPHS, POOL_CHUNKS), 256, 0, stream>>>(x1b, gstart, part);

    k_final<<<NUM_GRAPHS, HIDDEN, 0, stream>>>(part, gstart,
                                               Ws + 2 * HIDDEN * HIDDEN, bs + 2 * HIDDEN,
                                               linW, linb, out);
}